// Round 4
// baseline (2211.609 us; speedup 1.0000x reference)
//
#include <hip/hip_runtime.h>
#include <math.h>

#define NN 50000
#define EE 800000
#define GG 2000
#define HH 128
#define FN 64
#define FE 16

typedef short bf16x8 __attribute__((ext_vector_type(8)));
typedef float f32x4  __attribute__((ext_vector_type(4)));

// ---------------- device helpers ----------------
__device__ __forceinline__ float leakyf(float v){ return v>=0.f ? v : 0.01f*v; }
__device__ __forceinline__ float eluf(float v){ return v>0.f ? v : expm1f(v); }
__device__ __forceinline__ float sigmf(float v){ return 1.f/(1.f+__expf(-v)); }
__device__ __forceinline__ float tanh_fast(float x){
  float ax = fabsf(x);
  float e = __expf(-2.f*ax);
  float t = (1.f - e)/(1.f + e);
  return x>=0.f ? t : -t;
}
__device__ __forceinline__ int rdl(int v, int l){ return __builtin_amdgcn_readlane(v, l); }
__device__ __forceinline__ float rdlf(float v, int l){
  return __int_as_float(__builtin_amdgcn_readlane(__float_as_int(v), l));
}
__device__ __forceinline__ float wsum(float v){
#pragma unroll
  for(int m=32;m>=1;m>>=1) v += __shfl_xor(v,m,64);
  return v;
}
__device__ __forceinline__ float wmax64(float v){
#pragma unroll
  for(int m=32;m>=1;m>>=1) v = fmaxf(v,__shfl_xor(v,m,64));
  return v;
}

__device__ __forceinline__ f32x4 mfma16(bf16x8 a, bf16x8 b, f32x4 c){
  return __builtin_amdgcn_mfma_f32_16x16x32_bf16(a, b, c, 0, 0, 0);
}

// split 8 consecutive fp32 into bf16 hi (truncate) + bf16 lo (truncate of residual)
__device__ __forceinline__ void splitbf8(const float* p, bf16x8 &hi, bf16x8 &lo){
  float4 u = *(const float4*)p;
  float4 v = *(const float4*)(p+4);
  float f[8] = {u.x,u.y,u.z,u.w,v.x,v.y,v.z,v.w};
#pragma unroll
  for(int i=0;i<8;i++){
    unsigned b = __float_as_uint(f[i]);
    unsigned ht = b & 0xFFFF0000u;
    hi[i] = (short)(b >> 16);
    float r = f[i] - __uint_as_float(ht);
    lo[i] = (short)(__float_as_uint(r) >> 16);
  }
}

// ---------------- weight pre-split segment map (elements) ----------------
#define CV_LIN1   0        // 128x64  (ld 64)
#define CV_G1X    8192     // 128x128 from glin1W (ld 144, x-part cols 0..127)
#define CV_G2     24576    // 128x128
#define CV_ALIN   40960    // 2x128x128 dense
#define CV_MOL    73728    // 128x128
#define CV_G0IH   90112    // 384x128
#define CV_G0HH   139264
#define CV_AIH    188416   // 2x384x128 dense
#define CV_AHH    286720
#define CV_MIH    385024
#define CV_MHH    434176
#define CV_TOT    483328

__global__ void k_convw2(const float* __restrict__ lin1W, const float* __restrict__ glin1W,
                         const float* __restrict__ glin2W, const float* __restrict__ aLinW,
                         const float* __restrict__ aGWih, const float* __restrict__ aGWhh,
                         const float* __restrict__ mLinW, const float* __restrict__ mGWih,
                         const float* __restrict__ mGWhh, const float* __restrict__ g0Wih,
                         const float* __restrict__ g0Whh,
                         short* __restrict__ hi, short* __restrict__ lo){
  int i = blockIdx.x*256 + threadIdx.x;
  if(i >= CV_TOT) return;
  float v;
  if(i < CV_G1X){            v = lin1W[i];
  } else if(i < CV_G2){      int idx = i - CV_G1X; v = glin1W[(size_t)(idx>>7)*144 + (idx&127)];
  } else if(i < CV_ALIN){    v = glin2W[i - CV_G2];
  } else if(i < CV_MOL){     v = aLinW[i - CV_ALIN];
  } else if(i < CV_G0IH){    v = mLinW[i - CV_MOL];
  } else if(i < CV_G0HH){    v = g0Wih[i - CV_G0IH];
  } else if(i < CV_AIH){     v = g0Whh[i - CV_G0HH];
  } else if(i < CV_AHH){     v = aGWih[i - CV_AIH];
  } else if(i < CV_MIH){     v = aGWhh[i - CV_AHH];
  } else if(i < CV_MHH){     v = mGWih[i - CV_MIH];
  } else {                   v = mGWhh[i - CV_MHH];
  }
  unsigned b = __float_as_uint(v);
  unsigned ht = b & 0xFFFF0000u;
  hi[i] = (short)(b >> 16);
  float r = v - __uint_as_float(ht);
  lo[i] = (short)(__float_as_uint(r) >> 16);
}

// ---------------- CSR build ----------------
__global__ void k_count_edges(const int* __restrict__ dst, int* __restrict__ deg){
  int e = blockIdx.x*256 + threadIdx.x;
  if(e < EE) atomicAdd(&deg[dst[e]], 1);
}
__global__ void k_count_graphs(const int* __restrict__ batch, int* __restrict__ gcnt){
  int n = blockIdx.x*256 + threadIdx.x;
  if(n < NN) atomicAdd(&gcnt[batch[n]], 1);
}
__global__ void k_scan(const int* __restrict__ cnt, int* __restrict__ off, int n){
  __shared__ int part[1024];
  int t = threadIdx.x;
  int C = (n + 1023) >> 10;
  int lo = t*C, hic = min(lo + C, n);
  int s = 0;
  for(int i=lo;i<hic;i++) s += cnt[i];
  part[t] = s;
  __syncthreads();
  for(int o=1;o<1024;o<<=1){
    int v = (t>=o) ? part[t-o] : 0;
    __syncthreads();
    part[t] += v;
    __syncthreads();
  }
  int base = part[t] - s;
  int run = base;
  for(int i=lo;i<hic;i++){ run += cnt[i]; off[i+1] = run; }
  if(t==0) off[0] = 0;
}
__global__ void k_scatter_edges(const int* __restrict__ src, const int* __restrict__ dst,
                                const int* __restrict__ eoff, int* __restrict__ cur,
                                int* __restrict__ esrc_s, int* __restrict__ eperm){
  int e = blockIdx.x*256 + threadIdx.x;
  if(e < EE){
    int d = dst[e];
    int pos = eoff[d] + atomicAdd(&cur[d], 1);
    esrc_s[pos] = src[e];
    eperm[e] = pos;
  }
}

// ---------------- MFMA projection: C[M,128] = act(A[M,K] @ W[128,K]^T (+bias)) ----------------
// Split-bf16 (Markidis): hi*hi + hi*lo + lo*hi, fp32 accumulate.
// A-frag: row=lane&15, k=(lane>>4)*8+i.  B-frag: col(W row)=lane&15, same k.
// C/D: col=lane&15, row=(lane>>4)*4+reg  [guide-verified m89/m91].
template<int ACT, int K>
__global__ __launch_bounds__(256) void k_proj_mfma(const float* __restrict__ A,
                                                   const short* __restrict__ Whi,
                                                   const short* __restrict__ Wlo,
                                                   const float* __restrict__ bias,
                                                   float* __restrict__ C, int M){
  const int wave = threadIdx.x >> 6, lane = threadIdx.x & 63;
  const int m0 = blockIdx.x*64 + wave*16;
  const int lr = lane & 15, kg = lane >> 4;
  f32x4 acc[8];
#pragma unroll
  for(int t=0;t<8;t++) acc[t] = (f32x4){0.f,0.f,0.f,0.f};

  int arow = m0 + lr;
  int ar = arow < M ? arow : (M-1);

#pragma unroll
  for(int ks=0;ks<K;ks+=32){
    const int kb = ks + kg*8;
    bf16x8 ahi, alo;
    splitbf8(&A[(size_t)ar*K + kb], ahi, alo);
#pragma unroll
    for(int t=0;t<8;t++){
      const bf16x8 bh = *(const bf16x8*)&Whi[(size_t)(t*16+lr)*K + kb];
      const bf16x8 bl = *(const bf16x8*)&Wlo[(size_t)(t*16+lr)*K + kb];
      acc[t] = mfma16(ahi, bh, acc[t]);
      acc[t] = mfma16(ahi, bl, acc[t]);
      acc[t] = mfma16(alo, bh, acc[t]);
    }
  }
#pragma unroll
  for(int t=0;t<8;t++){
    int c = t*16 + lr;
#pragma unroll
    for(int r=0;r<4;r++){
      int m = m0 + kg*4 + r;
      if(m < M){
        float v = acc[t][r];
        if(ACT==1) v = leakyf(v + bias[c]);
        C[(size_t)m*HH + c] = v;
      }
    }
  }
}

// ---------------- fused MFMA GRUCell: XOUT = relu(GRU(MSG, X)) ----------------
// GI = MSG@Wih^T, GH = X@Whh^T, both [*,384], held in-register (24 tiles each).
// Gate triple (c, c+128, c+256) = tiles (t, t+8, t+16): same lane, same reg.
__global__ __launch_bounds__(256,2) void k_gru_mfma(const float* __restrict__ MSG,
                                                    const float* __restrict__ X,
                                                    const short* __restrict__ WIhi,
                                                    const short* __restrict__ WIlo,
                                                    const short* __restrict__ WHhi,
                                                    const short* __restrict__ WHlo,
                                                    const float* __restrict__ bih,
                                                    const float* __restrict__ bhh,
                                                    float* __restrict__ XOUT, int M){
  const int wave = threadIdx.x >> 6, lane = threadIdx.x & 63;
  const int m0 = blockIdx.x*64 + wave*16;
  const int lr = lane & 15, kg = lane >> 4;
  f32x4 accI[24], accH[24];
#pragma unroll
  for(int t=0;t<24;t++){ accI[t] = (f32x4){0.f,0.f,0.f,0.f}; accH[t] = (f32x4){0.f,0.f,0.f,0.f}; }

  int arow = m0 + lr;
  int ar = arow < M ? arow : (M-1);

#pragma unroll
  for(int ks=0;ks<HH;ks+=32){
    const int kb = ks + kg*8;
    bf16x8 mhi, mlo, xhi, xlo;
    splitbf8(&MSG[(size_t)ar*HH + kb], mhi, mlo);
    splitbf8(&X  [(size_t)ar*HH + kb], xhi, xlo);
#pragma unroll
    for(int t=0;t<24;t++){
      const size_t wo = (size_t)(t*16+lr)*HH + kb;
      const bf16x8 bih_ = *(const bf16x8*)&WIhi[wo];
      const bf16x8 bil_ = *(const bf16x8*)&WIlo[wo];
      accI[t] = mfma16(mhi, bih_, accI[t]);
      accI[t] = mfma16(mhi, bil_, accI[t]);
      accI[t] = mfma16(mlo, bih_, accI[t]);
      const bf16x8 bhh_ = *(const bf16x8*)&WHhi[wo];
      const bf16x8 bhl_ = *(const bf16x8*)&WHlo[wo];
      accH[t] = mfma16(xhi, bhh_, accH[t]);
      accH[t] = mfma16(xhi, bhl_, accH[t]);
      accH[t] = mfma16(xlo, bhh_, accH[t]);
    }
  }

#pragma unroll
  for(int t=0;t<8;t++){
    const int c = t*16 + lr;
    const float bir = bih[c], biz = bih[c+HH], bin = bih[c+2*HH];
    const float bhr = bhh[c], bhz = bhh[c+HH], bhn = bhh[c+2*HH];
#pragma unroll
    for(int r=0;r<4;r++){
      int m = m0 + kg*4 + r;
      if(m < M){
        float ir = accI[t][r]    + bir;
        float iz = accI[t+8][r]  + biz;
        float in_= accI[t+16][r] + bin;
        float hr = accH[t][r]    + bhr;
        float hz = accH[t+8][r]  + bhz;
        float hn = accH[t+16][r] + bhn;
        float rr = sigmf(ir + hr);
        float z  = sigmf(iz + hz);
        float ng = tanh_fast(in_ + rr*hn);
        float hp = X[(size_t)m*HH + c];
        XOUT[(size_t)m*HH + c] = fmaxf((1.f - z)*ng + z*hp, 0.f);
      }
    }
  }
}

// ---------------- GATEConv edge alpha (unchanged: round-3 control, 209us) ----------------
__global__ __launch_bounds__(256) void k_gate_alpha2(const float* __restrict__ XP,
                                                     const float* __restrict__ EA,
                                                     const int* __restrict__ esrc,
                                                     const int* __restrict__ edst,
                                                     const float* __restrict__ W1,
                                                     const float* __restrict__ attl,
                                                     const float* __restrict__ RD,
                                                     const int* __restrict__ eperm,
                                                     float* __restrict__ ALPHA){
  const int lane = threadIdx.x & 63;
  const int wid = (blockIdx.x*blockDim.x + threadIdx.x) >> 6;
  const int nw  = (gridDim.x*blockDim.x) >> 6;

  float we0[16], we1[16];
#pragma unroll
  for(int f=0;f<16;f++){
    we0[f] = W1[(size_t)lane*144 + 128 + f];
    we1[f] = W1[(size_t)(lane+64)*144 + 128 + f];
  }
  const float al0 = attl[lane], al1 = attl[64+lane];

  for(int c0 = wid*64; c0 < EE; c0 += nw*64){
    const int e = c0 + lane;
    const int sIdx = esrc[e];
    const int dIdx = edst[e];
    const int pIdx = eperm[e];
    float ea[16];
    {
      const float4* g = (const float4*)&EA[(size_t)e*FE];
      float4 v0=g[0], v1=g[1], v2=g[2], v3=g[3];
      ea[0]=v0.x;ea[1]=v0.y;ea[2]=v0.z;ea[3]=v0.w;
      ea[4]=v1.x;ea[5]=v1.y;ea[6]=v1.z;ea[7]=v1.w;
      ea[8]=v2.x;ea[9]=v2.y;ea[10]=v2.z;ea[11]=v2.w;
      ea[12]=v3.x;ea[13]=v3.y;ea[14]=v3.z;ea[15]=v3.w;
    }
#pragma unroll 1
    for(int j=0;j<64;j++){
      const int sj = rdl(sIdx, j);
      float xp0 = XP[(size_t)sj*HH + lane];
      float xp1 = XP[(size_t)sj*HH + 64 + lane];
      float e0 = 0.f, e1 = 0.f;
#pragma unroll
      for(int f=0;f<16;f++){
        float wv = rdlf(ea[f], j);
        e0 += wv*we0[f]; e1 += wv*we1[f];
      }
      float p = leakyf(xp0+e0)*al0 + leakyf(xp1+e1)*al1;
      p = wsum(p);
      const int dj = rdl(dIdx, j);
      const int pj = rdl(pIdx, j);
      if(lane==0){
        ALPHA[pj] = leakyf(p + RD[dj]);
      }
    }
  }
}

// ---------------- segment softmax + weighted aggregation (online, one pass) ----------------
template<int MODE>
__global__ void k_agg(const int* __restrict__ off, const int* __restrict__ items,
                      const float* __restrict__ ALPHA, const float* __restrict__ A1,
                      const float* __restrict__ A2, const float* __restrict__ XSrc,
                      const float* __restrict__ bias, float* __restrict__ OUT, int nseg){
  int w = (blockIdx.x*blockDim.x + threadIdx.x) >> 6;
  int lane = threadIdx.x & 63;
  if(w >= nseg) return;
  int s0 = off[w], s1 = off[w+1];
  float a2 = (MODE==0) ? 0.f : A2[w];

  float m = -INFINITY, s = 0.f, h0 = 0.f, h1 = 0.f;

  for(int c0=s0;c0<s1;c0+=64){
    int n = min(64, s1-c0);
    int it = 0;
    float a = -INFINITY;
    if(lane < n){
      int i = c0 + lane;
      it = (MODE==2) ? i : items[i];
      if(MODE==0) a = ALPHA[i];
      else a = leakyf(A1[it] + a2);
    }
    float cm = wmax64(a);
    float mN = fmaxf(m, cm);
    float scale = (m == -INFINITY) ? 0.f : __expf(m - mN);
    float e = (lane < n) ? __expf(a - mN) : 0.f;
    s = s*scale + wsum(e);
    h0 *= scale; h1 *= scale;
    m = mN;
#pragma unroll 4
    for(int j=0;j<n;j++){
      int itj = rdl(it, j);
      float wg = rdlf(e, j);
      h0 += wg * XSrc[(size_t)itj*HH + lane];
      h1 += wg * XSrc[(size_t)itj*HH + 64 + lane];
    }
  }
  float inv = 1.f/(s + 1e-16f);
  h0 = h0*inv + bias[lane];
  h1 = h1*inv + bias[64+lane];
  OUT[(size_t)w*HH + lane]      = eluf(h0);
  OUT[(size_t)w*HH + 64 + lane] = eluf(h1);
}

// ---------------- small per-row kernels ----------------
__global__ void k_dot2(const float* __restrict__ X, const float* __restrict__ u,
                       const float* __restrict__ v, float* __restrict__ a,
                       float* __restrict__ b, int M){
  int w = (blockIdx.x*blockDim.x + threadIdx.x) >> 6;
  int lane = threadIdx.x & 63;
  if(w >= M) return;
  float x0 = X[(size_t)w*HH + lane];
  float x1 = X[(size_t)w*HH + 64 + lane];
  float p = x0*u[lane] + x1*u[64+lane];
  p = wsum(p);
  if(lane==0) a[w] = p;
  if(v){
    float q = x0*v[lane] + x1*v[64+lane];
    q = wsum(q);
    if(lane==0) b[w] = q;
  }
}

__global__ void k_ginit(const int* __restrict__ goff, const float* __restrict__ X,
                        float* __restrict__ OUT){
  int g = (blockIdx.x*blockDim.x + threadIdx.x) >> 6;
  int lane = threadIdx.x & 63;
  if(g >= GG) return;
  int s0 = goff[g], s1 = goff[g+1];
  float h0=0.f, h1=0.f;
  for(int n=s0;n<s1;n++){
    h0 += X[(size_t)n*HH + lane];
    h1 += X[(size_t)n*HH + 64 + lane];
  }
  OUT[(size_t)g*HH + lane]      = fmaxf(h0, 0.f);
  OUT[(size_t)g*HH + 64 + lane] = fmaxf(h1, 0.f);
}

__global__ void k_weff(const float* __restrict__ lin2W, const float* __restrict__ lin2b,
                       const float* __restrict__ finW, const float* __restrict__ finb,
                       float* __restrict__ weff){
  int c = threadIdx.x;
  float s = 0.f;
  for(int j=0;j<HH;j++) s += finW[j]*lin2W[(size_t)j*HH + c];
  weff[c] = s;
  if(c==0){
    float bb = finb[0];
    for(int j=0;j<HH;j++) bb += lin2b[j]*finW[j];
    weff[HH] = bb;
  }
}

__global__ void k_final(const float* __restrict__ OUT, const float* __restrict__ weff,
                        float* __restrict__ y){
  int g = (blockIdx.x*blockDim.x + threadIdx.x) >> 6;
  int lane = threadIdx.x & 63;
  if(g >= GG) return;
  float p = OUT[(size_t)g*HH + lane]*weff[lane] + OUT[(size_t)g*HH + 64 + lane]*weff[64+lane];
  p = wsum(p);
  if(lane==0) y[g] = sigmf(p + weff[HH]);
}

// ---------------- host ----------------
extern "C" void kernel_launch(void* const* d_in, const int* in_sizes, int n_in,
                              void* d_out, int out_size, void* d_ws, size_t ws_size,
                              hipStream_t stream){
  const float* in_x   = (const float*)d_in[0];
  const int*   eidx   = (const int*)d_in[1];
  const float* ea     = (const float*)d_in[2];
  const int*   batch  = (const int*)d_in[3];
  const float* lin1W  = (const float*)d_in[4];
  const float* lin1b  = (const float*)d_in[5];
  const float* gattl  = (const float*)d_in[6];
  const float* gattr  = (const float*)d_in[7];
  const float* glin1W = (const float*)d_in[8];
  const float* glin2W = (const float*)d_in[9];
  const float* gbias  = (const float*)d_in[10];
  const float* g0Wih  = (const float*)d_in[11];
  const float* g0Whh  = (const float*)d_in[12];
  const float* g0bih  = (const float*)d_in[13];
  const float* g0bhh  = (const float*)d_in[14];
  const float* aLinW  = (const float*)d_in[15];
  const float* aAttS  = (const float*)d_in[16];
  const float* aAttD  = (const float*)d_in[17];
  const float* aBias  = (const float*)d_in[18];
  const float* aGWih  = (const float*)d_in[19];
  const float* aGWhh  = (const float*)d_in[20];
  const float* aGbih  = (const float*)d_in[21];
  const float* aGbhh  = (const float*)d_in[22];
  const float* mLinW  = (const float*)d_in[23];
  const float* mAttS  = (const float*)d_in[24];
  const float* mAttD  = (const float*)d_in[25];
  const float* mBias  = (const float*)d_in[26];
  const float* mGWih  = (const float*)d_in[27];
  const float* mGWhh  = (const float*)d_in[28];
  const float* mGbih  = (const float*)d_in[29];
  const float* mGbhh  = (const float*)d_in[30];
  const float* lin2W  = (const float*)d_in[31];
  const float* lin2b  = (const float*)d_in[32];
  const float* finW   = (const float*)d_in[33];
  const float* finb   = (const float*)d_in[34];

  const int* esrc0 = eidx;
  const int* edst0 = eidx + EE;

  char* w = (char*)d_ws;
  size_t o = 0;
  auto alloc = [&](size_t bytes)->void*{
    void* p = w + o;
    o = (o + bytes + 255) & ~(size_t)255;
    return p;
  };
  float* X    = (float*)alloc((size_t)NN*HH*4);
  float* XB   = (float*)alloc((size_t)NN*HH*4);
  float* XS   = (float*)alloc((size_t)NN*HH*4);
  float* MSG  = (float*)alloc((size_t)NN*HH*4);
  float* XP   = (float*)alloc((size_t)NN*HH*4);
  float* ALPHA= (float*)alloc((size_t)EE*4);
  float* S1   = (float*)alloc((size_t)NN*4);
  float* S2   = (float*)alloc((size_t)NN*4);
  float* ADSTG= (float*)alloc((size_t)GG*4);
  float* OUTg = (float*)alloc((size_t)GG*HH*4);
  float* OUTb = (float*)alloc((size_t)GG*HH*4);
  float* HG   = (float*)alloc((size_t)GG*HH*4);
  float* ODg  = (float*)alloc((size_t)GG*HH*4);
  float* WEFF = (float*)alloc(256*4);
  short* cWhi = (short*)alloc((size_t)CV_TOT*2);
  short* cWlo = (short*)alloc((size_t)CV_TOT*2);
  int* zeroreg= (int*)alloc((size_t)(NN + NN + 2048)*4);
  int* deg  = zeroreg;
  int* cur  = zeroreg + NN;
  int* gcnt = zeroreg + 2*NN;
  int* eoff = (int*)alloc((size_t)(NN+1)*4);
  int* goff = (int*)alloc((size_t)(GG+1)*4);
  int* esrcS= (int*)alloc((size_t)EE*4);
  int* eperm= (int*)alloc((size_t)EE*4);

  const short* c_lin1_h = cWhi + CV_LIN1; const short* c_lin1_l = cWlo + CV_LIN1;
  const short* c_g1x_h  = cWhi + CV_G1X;  const short* c_g1x_l  = cWlo + CV_G1X;
  const short* c_g2_h   = cWhi + CV_G2;   const short* c_g2_l   = cWlo + CV_G2;
  const short* c_mol_h  = cWhi + CV_MOL;  const short* c_mol_l  = cWlo + CV_MOL;
  const short* c_g0ih_h = cWhi + CV_G0IH; const short* c_g0ih_l = cWlo + CV_G0IH;
  const short* c_g0hh_h = cWhi + CV_G0HH; const short* c_g0hh_l = cWlo + CV_G0HH;
  const short* c_mih_h  = cWhi + CV_MIH;  const short* c_mih_l  = cWlo + CV_MIH;
  const short* c_mhh_h  = cWhi + CV_MHH;  const short* c_mhh_l  = cWlo + CV_MHH;

  // ---- weight pre-split (bf16 hi/lo) ----
  k_convw2<<<(CV_TOT+255)/256, 256, 0, stream>>>(lin1W, glin1W, glin2W, aLinW, aGWih, aGWhh,
                                                 mLinW, mGWih, mGWhh, g0Wih, g0Whh, cWhi, cWlo);

  // ---- CSR build ----
  hipMemsetAsync(zeroreg, 0, (size_t)(NN + NN + 2048)*4, stream);
  k_count_edges<<<EE/256, 256, 0, stream>>>(edst0, deg);
  k_scan<<<1, 1024, 0, stream>>>(deg, eoff, NN);
  k_scatter_edges<<<EE/256, 256, 0, stream>>>(esrc0, edst0, eoff, cur, esrcS, eperm);
  k_count_graphs<<<(NN+255)/256, 256, 0, stream>>>(batch, gcnt);
  k_scan<<<1, 1024, 0, stream>>>(gcnt, goff, GG);

  const int gN = (NN + 63)/64;   // 782
  const int gG = (GG + 63)/64;   // 32

  // ---- input projection: X = leaky(x @ lin1W^T + lin1b) ----
  k_proj_mfma<1,64><<<gN, 256, 0, stream>>>(in_x, c_lin1_h, c_lin1_l, lin1b, X, NN);

  // ---- GATEConv ----
  k_dot2<<<(NN+3)/4, 256, 0, stream>>>(X, gattr, nullptr, S1, nullptr, NN);
  k_proj_mfma<0,128><<<gN, 256, 0, stream>>>(X, c_g1x_h, c_g1x_l, nullptr, XP, NN);
  k_proj_mfma<0,128><<<gN, 256, 0, stream>>>(X, c_g2_h, c_g2_l, nullptr, XS, NN);
  k_gate_alpha2<<<1024, 256, 0, stream>>>(XP, ea, esrc0, edst0, glin1W, gattl, S1, eperm, ALPHA);
  k_agg<0><<<(NN+3)/4, 256, 0, stream>>>(eoff, esrcS, ALPHA, nullptr, nullptr, XS, gbias, MSG, NN);
  k_gru_mfma<<<gN, 256, 0, stream>>>(MSG, X, c_g0ih_h, c_g0ih_l, c_g0hh_h, c_g0hh_l,
                                     g0bih, g0bhh, XB, NN);
  { float* t = X; X = XB; XB = t; }

  // ---- atom GATConv layers ----
  for(int l=0;l<2;l++){
    const short* c_a_h   = cWhi + CV_ALIN + (size_t)l*HH*HH;
    const short* c_a_l   = cWlo + CV_ALIN + (size_t)l*HH*HH;
    const short* c_aih_h = cWhi + CV_AIH + (size_t)l*3*HH*HH;
    const short* c_aih_l = cWlo + CV_AIH + (size_t)l*3*HH*HH;
    const short* c_ahh_h = cWhi + CV_AHH + (size_t)l*3*HH*HH;
    const short* c_ahh_l = cWlo + CV_AHH + (size_t)l*3*HH*HH;
    const float* asl  = aAttS + (size_t)l*HH;
    const float* adl  = aAttD + (size_t)l*HH;
    const float* bl   = aBias + (size_t)l*HH;
    const float* bi   = aGbih + (size_t)l*3*HH;
    const float* bh   = aGbhh + (size_t)l*3*HH;
    k_proj_mfma<0,128><<<gN, 256, 0, stream>>>(X, c_a_h, c_a_l, nullptr, XS, NN);
    k_dot2<<<(NN+3)/4, 256, 0, stream>>>(XS, asl, adl, S1, S2, NN);
    k_agg<1><<<(NN+3)/4, 256, 0, stream>>>(eoff, esrcS, nullptr, S1, S2, XS, bl, MSG, NN);
    k_gru_mfma<<<gN, 256, 0, stream>>>(MSG, X, c_aih_h, c_aih_l, c_ahh_h, c_ahh_l, bi, bh, XB, NN);
    { float* t = X; X = XB; XB = t; }
  }

  // ---- molecule readout ----
  k_ginit<<<(GG+3)/4, 256, 0, stream>>>(goff, X, OUTg);
  k_proj_mfma<0,128><<<gN, 256, 0, stream>>>(X, c_mol_h, c_mol_l, nullptr, XS, NN);
  k_dot2<<<(NN+3)/4, 256, 0, stream>>>(XS, mAttS, nullptr, S1, nullptr, NN);

  float* Ocur = OUTg;
  float* Onxt = OUTb;
  for(int t=0;t<3;t++){
    k_proj_mfma<0,128><<<gG, 256, 0, stream>>>(Ocur, c_mol_h, c_mol_l, nullptr, ODg, GG);
    k_dot2<<<(GG+3)/4, 256, 0, stream>>>(ODg, mAttD, nullptr, ADSTG, nullptr, GG);
    k_agg<2><<<(GG+3)/4, 256, 0, stream>>>(goff, nullptr, nullptr, S1, ADSTG, XS, mBias, HG, GG);
    k_gru_mfma<<<gG, 256, 0, stream>>>(HG, Ocur, c_mih_h, c_mih_l, c_mhh_h, c_mhh_l,
                                       mGbih, mGbhh, Onxt, GG);
    { float* tt = Ocur; Ocur = Onxt; Onxt = tt; }
  }

  // ---- fused lin2 + final ----
  k_weff<<<1, 128, 0, stream>>>(lin2W, lin2b, finW, finb, WEFF);
  k_final<<<(GG+3)/4, 256, 0, stream>>>(Ocur, WEFF, (float*)d_out);
}

// Round 5
// 1836.404 us; speedup vs baseline: 1.2043x; 1.2043x over previous
//
#include <hip/hip_runtime.h>
#include <math.h>

#define NN 50000
#define EE 800000
#define GG 2000
#define HH 128
#define FN 64
#define FE 16

typedef short bf16x8 __attribute__((ext_vector_type(8)));
typedef float f32x4  __attribute__((ext_vector_type(4)));

// ---------------- device helpers ----------------
__device__ __forceinline__ float leakyf(float v){ return v>=0.f ? v : 0.01f*v; }
__device__ __forceinline__ float eluf(float v){ return v>0.f ? v : expm1f(v); }
__device__ __forceinline__ float sigmf(float v){ return 1.f/(1.f+__expf(-v)); }
__device__ __forceinline__ float tanh_fast(float x){
  float ax = fabsf(x);
  float e = __expf(-2.f*ax);
  float t = (1.f - e)/(1.f + e);
  return x>=0.f ? t : -t;
}
__device__ __forceinline__ int rdl(int v, int l){ return __builtin_amdgcn_readlane(v, l); }
__device__ __forceinline__ float rdlf(float v, int l){
  return __int_as_float(__builtin_amdgcn_readlane(__float_as_int(v), l));
}
__device__ __forceinline__ float wsum(float v){
#pragma unroll
  for(int m=32;m>=1;m>>=1) v += __shfl_xor(v,m,64);
  return v;
}
__device__ __forceinline__ float wmax64(float v){
#pragma unroll
  for(int m=32;m>=1;m>>=1) v = fmaxf(v,__shfl_xor(v,m,64));
  return v;
}

__device__ __forceinline__ f32x4 mfma16(bf16x8 a, bf16x8 b, f32x4 c){
  return __builtin_amdgcn_mfma_f32_16x16x32_bf16(a, b, c, 0, 0, 0);
}

// split 8 consecutive fp32 into bf16 hi (truncate) + bf16 lo (truncate of residual)
__device__ __forceinline__ void splitbf8(const float* p, bf16x8 &hi, bf16x8 &lo){
  float4 u = *(const float4*)p;
  float4 v = *(const float4*)(p+4);
  float f[8] = {u.x,u.y,u.z,u.w,v.x,v.y,v.z,v.w};
#pragma unroll
  for(int i=0;i<8;i++){
    unsigned b = __float_as_uint(f[i]);
    unsigned ht = b & 0xFFFF0000u;
    hi[i] = (short)(b >> 16);
    float r = f[i] - __uint_as_float(ht);
    lo[i] = (short)(__float_as_uint(r) >> 16);
  }
}

// ---------------- weight pre-split segment map (elements) ----------------
#define CV_LIN1   0        // 128x64  (ld 64)
#define CV_G1X    8192     // 128x128 from glin1W (ld 144, x-part cols 0..127)
#define CV_G2     24576    // 128x128
#define CV_ALIN   40960    // 2x128x128 dense
#define CV_MOL    73728    // 128x128
#define CV_G0IH   90112    // 384x128
#define CV_G0HH   139264
#define CV_AIH    188416   // 2x384x128 dense
#define CV_AHH    286720
#define CV_MIH    385024
#define CV_MHH    434176
#define CV_TOT    483328

__global__ void k_convw2(const float* __restrict__ lin1W, const float* __restrict__ glin1W,
                         const float* __restrict__ glin2W, const float* __restrict__ aLinW,
                         const float* __restrict__ aGWih, const float* __restrict__ aGWhh,
                         const float* __restrict__ mLinW, const float* __restrict__ mGWih,
                         const float* __restrict__ mGWhh, const float* __restrict__ g0Wih,
                         const float* __restrict__ g0Whh,
                         short* __restrict__ hi, short* __restrict__ lo){
  int i = blockIdx.x*256 + threadIdx.x;
  if(i >= CV_TOT) return;
  float v;
  if(i < CV_G1X){            v = lin1W[i];
  } else if(i < CV_G2){      int idx = i - CV_G1X; v = glin1W[(size_t)(idx>>7)*144 + (idx&127)];
  } else if(i < CV_ALIN){    v = glin2W[i - CV_G2];
  } else if(i < CV_MOL){     v = aLinW[i - CV_ALIN];
  } else if(i < CV_G0IH){    v = mLinW[i - CV_MOL];
  } else if(i < CV_G0HH){    v = g0Wih[i - CV_G0IH];
  } else if(i < CV_AIH){     v = g0Whh[i - CV_G0HH];
  } else if(i < CV_AHH){     v = aGWih[i - CV_AIH];
  } else if(i < CV_MIH){     v = aGWhh[i - CV_AHH];
  } else if(i < CV_MHH){     v = mGWih[i - CV_MIH];
  } else {                   v = mGWhh[i - CV_MHH];
  }
  unsigned b = __float_as_uint(v);
  unsigned ht = b & 0xFFFF0000u;
  hi[i] = (short)(b >> 16);
  float r = v - __uint_as_float(ht);
  lo[i] = (short)(__float_as_uint(r) >> 16);
}

// ---------------- CSR build ----------------
__global__ void k_count_edges(const int* __restrict__ dst, int* __restrict__ deg){
  int e = blockIdx.x*256 + threadIdx.x;
  if(e < EE) atomicAdd(&deg[dst[e]], 1);
}
__global__ void k_count_graphs(const int* __restrict__ batch, int* __restrict__ gcnt){
  int n = blockIdx.x*256 + threadIdx.x;
  if(n < NN) atomicAdd(&gcnt[batch[n]], 1);
}
__global__ void k_scan(const int* __restrict__ cnt, int* __restrict__ off, int n){
  __shared__ int part[1024];
  int t = threadIdx.x;
  int C = (n + 1023) >> 10;
  int lo = t*C, hic = min(lo + C, n);
  int s = 0;
  for(int i=lo;i<hic;i++) s += cnt[i];
  part[t] = s;
  __syncthreads();
  for(int o=1;o<1024;o<<=1){
    int v = (t>=o) ? part[t-o] : 0;
    __syncthreads();
    part[t] += v;
    __syncthreads();
  }
  int base = part[t] - s;
  int run = base;
  for(int i=lo;i<hic;i++){ run += cnt[i]; off[i+1] = run; }
  if(t==0) off[0] = 0;
}
__global__ void k_scatter_edges(const int* __restrict__ src, const int* __restrict__ dst,
                                const int* __restrict__ eoff, int* __restrict__ cur,
                                int* __restrict__ esrc_s, int* __restrict__ eperm){
  int e = blockIdx.x*256 + threadIdx.x;
  if(e < EE){
    int d = dst[e];
    int pos = eoff[d] + atomicAdd(&cur[d], 1);
    esrc_s[pos] = src[e];
    eperm[e] = pos;
  }
}

// ---------------- MFMA projection: C[M,128] = act(A[M,K] @ W[128,K]^T (+bias)) ----------------
// Split-bf16 (Markidis): hi*hi + hi*lo + lo*hi, fp32 accumulate.
// A-frag: row=lane&15, k=(lane>>4)*8+i.  C/D: col=lane&15, row=(lane>>4)*4+reg.
// Layouts HW-verified by round-4 pass (absmax 0.002 = split-bf16 rounding only).
template<int ACT, int K>
__global__ __launch_bounds__(256) void k_proj_mfma(const float* __restrict__ A,
                                                   const short* __restrict__ Whi,
                                                   const short* __restrict__ Wlo,
                                                   const float* __restrict__ bias,
                                                   float* __restrict__ C, int M){
  const int wave = threadIdx.x >> 6, lane = threadIdx.x & 63;
  const int m0 = blockIdx.x*64 + wave*16;
  const int lr = lane & 15, kg = lane >> 4;
  f32x4 acc[8];
#pragma unroll
  for(int t=0;t<8;t++) acc[t] = (f32x4){0.f,0.f,0.f,0.f};

  int arow = m0 + lr;
  int ar = arow < M ? arow : (M-1);

#pragma unroll
  for(int ks=0;ks<K;ks+=32){
    const int kb = ks + kg*8;
    bf16x8 ahi, alo;
    splitbf8(&A[(size_t)ar*K + kb], ahi, alo);
#pragma unroll
    for(int t=0;t<8;t++){
      const bf16x8 bh = *(const bf16x8*)&Whi[(size_t)(t*16+lr)*K + kb];
      const bf16x8 bl = *(const bf16x8*)&Wlo[(size_t)(t*16+lr)*K + kb];
      acc[t] = mfma16(ahi, bh, acc[t]);
      acc[t] = mfma16(ahi, bl, acc[t]);
      acc[t] = mfma16(alo, bh, acc[t]);
    }
  }
#pragma unroll
  for(int t=0;t<8;t++){
    int c = t*16 + lr;
#pragma unroll
    for(int r=0;r<4;r++){
      int m = m0 + kg*4 + r;
      if(m < M){
        float v = acc[t][r];
        if(ACT==1) v = leakyf(v + bias[c]);
        C[(size_t)m*HH + c] = v;
      }
    }
  }
}

// ---------------- fused MFMA GRUCell v2: XOUT = relu(GRU(MSG, X)) ----------------
// Anti-spill restructure: A-fragments (MSG,X hi+lo, all 4 K-slices) precomputed once
// (16 bf16x8 = 64 VGPR); loop col-tile groups t=0..7 with only ONE gate-triple live:
// 6 f32x4 acc (24 VGPR). Gate math + store per group. No launch_bounds min-waves ->
// compiler free up to 256 VGPR, no scratch. (R4 failure: 48 acc tiles vs 128-VGPR cap.)
__global__ __launch_bounds__(256) void k_gru_mfma(const float* __restrict__ MSG,
                                                  const float* __restrict__ X,
                                                  const short* __restrict__ WIhi,
                                                  const short* __restrict__ WIlo,
                                                  const short* __restrict__ WHhi,
                                                  const short* __restrict__ WHlo,
                                                  const float* __restrict__ bih,
                                                  const float* __restrict__ bhh,
                                                  float* __restrict__ XOUT, int M){
  const int wave = threadIdx.x >> 6, lane = threadIdx.x & 63;
  const int m0 = blockIdx.x*64 + wave*16;
  const int lr = lane & 15, kg = lane >> 4;
  int arow = m0 + lr;
  int ar = arow < M ? arow : (M-1);

  bf16x8 mh[4], ml[4], xh[4], xl[4];
#pragma unroll
  for(int ks=0;ks<4;ks++){
    splitbf8(&MSG[(size_t)ar*HH + ks*32 + kg*8], mh[ks], ml[ks]);
    splitbf8(&X  [(size_t)ar*HH + ks*32 + kg*8], xh[ks], xl[ks]);
  }

#pragma unroll 1
  for(int t=0;t<8;t++){
    f32x4 aIr = (f32x4){0.f,0.f,0.f,0.f}, aIz = aIr, aIn = aIr;
    f32x4 aHr = aIr, aHz = aIr, aHn = aIr;
    const size_t rbase = (size_t)(t*16 + lr)*HH;
#pragma unroll
    for(int ks=0;ks<4;ks++){
      const int kb = ks*32 + kg*8;
      const size_t o0 = rbase + kb;                    // gate r row block
      const size_t o1 = o0 + (size_t)128*HH;           // gate z
      const size_t o2 = o1 + (size_t)128*HH;           // gate n
      bf16x8 bh_, bl_;
      bh_ = *(const bf16x8*)&WIhi[o0]; bl_ = *(const bf16x8*)&WIlo[o0];
      aIr = mfma16(mh[ks], bh_, aIr); aIr = mfma16(mh[ks], bl_, aIr); aIr = mfma16(ml[ks], bh_, aIr);
      bh_ = *(const bf16x8*)&WIhi[o1]; bl_ = *(const bf16x8*)&WIlo[o1];
      aIz = mfma16(mh[ks], bh_, aIz); aIz = mfma16(mh[ks], bl_, aIz); aIz = mfma16(ml[ks], bh_, aIz);
      bh_ = *(const bf16x8*)&WIhi[o2]; bl_ = *(const bf16x8*)&WIlo[o2];
      aIn = mfma16(mh[ks], bh_, aIn); aIn = mfma16(mh[ks], bl_, aIn); aIn = mfma16(ml[ks], bh_, aIn);
      bh_ = *(const bf16x8*)&WHhi[o0]; bl_ = *(const bf16x8*)&WHlo[o0];
      aHr = mfma16(xh[ks], bh_, aHr); aHr = mfma16(xh[ks], bl_, aHr); aHr = mfma16(xl[ks], bh_, aHr);
      bh_ = *(const bf16x8*)&WHhi[o1]; bl_ = *(const bf16x8*)&WHlo[o1];
      aHz = mfma16(xh[ks], bh_, aHz); aHz = mfma16(xh[ks], bl_, aHz); aHz = mfma16(xl[ks], bh_, aHz);
      bh_ = *(const bf16x8*)&WHhi[o2]; bl_ = *(const bf16x8*)&WHlo[o2];
      aHn = mfma16(xh[ks], bh_, aHn); aHn = mfma16(xh[ks], bl_, aHn); aHn = mfma16(xl[ks], bh_, aHn);
    }
    const int c = t*16 + lr;
    const float bir = bih[c], biz = bih[c+HH], bin = bih[c+2*HH];
    const float bhr = bhh[c], bhz = bhh[c+HH], bhn = bhh[c+2*HH];
#pragma unroll
    for(int r=0;r<4;r++){
      int mm = m0 + kg*4 + r;
      if(mm < M){
        float ir = aIr[r]+bir, iz = aIz[r]+biz, in_ = aIn[r]+bin;
        float hr = aHr[r]+bhr, hz = aHz[r]+bhz, hn = aHn[r]+bhn;
        float rr = sigmf(ir + hr);
        float z  = sigmf(iz + hz);
        float ng = tanh_fast(in_ + rr*hn);
        float hp = X[(size_t)mm*HH + c];
        XOUT[(size_t)mm*HH + c] = fmaxf((1.f - z)*ng + z*hp, 0.f);
      }
    }
  }
}

// ---------------- GATEConv edge alpha (float2 rows + unroll 4) ----------------
__global__ __launch_bounds__(256) void k_gate_alpha2(const float* __restrict__ XP,
                                                     const float* __restrict__ EA,
                                                     const int* __restrict__ esrc,
                                                     const int* __restrict__ edst,
                                                     const float* __restrict__ W1,
                                                     const float* __restrict__ attl,
                                                     const float* __restrict__ RD,
                                                     const int* __restrict__ eperm,
                                                     float* __restrict__ ALPHA){
  const int lane = threadIdx.x & 63;
  const int wid = (blockIdx.x*blockDim.x + threadIdx.x) >> 6;
  const int nw  = (gridDim.x*blockDim.x) >> 6;

  // lane covers columns 2*lane, 2*lane+1
  float wea[16], web[16];
#pragma unroll
  for(int f=0;f<16;f++){
    wea[f] = W1[(size_t)(2*lane)*144 + 128 + f];
    web[f] = W1[(size_t)(2*lane+1)*144 + 128 + f];
  }
  const float al0 = attl[2*lane], al1 = attl[2*lane+1];

  for(int c0 = wid*64; c0 < EE; c0 += nw*64){
    const int e = c0 + lane;
    const int sIdx = esrc[e];
    const int dIdx = edst[e];
    const int pIdx = eperm[e];
    float ea[16];
    {
      const float4* g = (const float4*)&EA[(size_t)e*FE];
      float4 v0=g[0], v1=g[1], v2=g[2], v3=g[3];
      ea[0]=v0.x;ea[1]=v0.y;ea[2]=v0.z;ea[3]=v0.w;
      ea[4]=v1.x;ea[5]=v1.y;ea[6]=v1.z;ea[7]=v1.w;
      ea[8]=v2.x;ea[9]=v2.y;ea[10]=v2.z;ea[11]=v2.w;
      ea[12]=v3.x;ea[13]=v3.y;ea[14]=v3.z;ea[15]=v3.w;
    }
#pragma unroll 4
    for(int j=0;j<64;j++){
      const int sj = rdl(sIdx, j);
      float2 xp = *(const float2*)&XP[(size_t)sj*HH + 2*lane];
      float e0 = 0.f, e1 = 0.f;
#pragma unroll
      for(int f=0;f<16;f++){
        float wv = rdlf(ea[f], j);
        e0 += wv*wea[f]; e1 += wv*web[f];
      }
      float p = leakyf(xp.x+e0)*al0 + leakyf(xp.y+e1)*al1;
      p = wsum(p);
      const int dj = rdl(dIdx, j);
      const int pj = rdl(pIdx, j);
      if(lane==0){
        ALPHA[pj] = leakyf(p + RD[dj]);
      }
    }
  }
}

// ---------------- segment softmax + weighted aggregation (online, float2 rows) ----------------
template<int MODE>
__global__ void k_agg(const int* __restrict__ off, const int* __restrict__ items,
                      const float* __restrict__ ALPHA, const float* __restrict__ A1,
                      const float* __restrict__ A2, const float* __restrict__ XSrc,
                      const float* __restrict__ bias, float* __restrict__ OUT, int nseg){
  int w = (blockIdx.x*blockDim.x + threadIdx.x) >> 6;
  int lane = threadIdx.x & 63;
  if(w >= nseg) return;
  int s0 = off[w], s1 = off[w+1];
  float a2 = (MODE==0) ? 0.f : A2[w];

  float m = -INFINITY, s = 0.f;
  float hx = 0.f, hy = 0.f;

  for(int c0=s0;c0<s1;c0+=64){
    int n = min(64, s1-c0);
    int it = 0;
    float a = -INFINITY;
    if(lane < n){
      int i = c0 + lane;
      it = (MODE==2) ? i : items[i];
      if(MODE==0) a = ALPHA[i];
      else a = leakyf(A1[it] + a2);
    }
    float cm = wmax64(a);
    float mN = fmaxf(m, cm);
    float scale = (m == -INFINITY) ? 0.f : __expf(m - mN);
    float e = (lane < n) ? __expf(a - mN) : 0.f;
    s = s*scale + wsum(e);
    hx *= scale; hy *= scale;
    m = mN;
#pragma unroll 8
    for(int j=0;j<n;j++){
      int itj = rdl(it, j);
      float wg = rdlf(e, j);
      float2 xv = *(const float2*)&XSrc[(size_t)itj*HH + 2*lane];
      hx += wg * xv.x;
      hy += wg * xv.y;
    }
  }
  float inv = 1.f/(s + 1e-16f);
  float2 bv = *(const float2*)&bias[2*lane];
  float2 o;
  o.x = eluf(hx*inv + bv.x);
  o.y = eluf(hy*inv + bv.y);
  *(float2*)&OUT[(size_t)w*HH + 2*lane] = o;
}

// ---------------- small per-row kernels (float2 rows) ----------------
__global__ void k_dot2(const float* __restrict__ X, const float* __restrict__ u,
                       const float* __restrict__ v, float* __restrict__ a,
                       float* __restrict__ b, int M){
  int w = (blockIdx.x*blockDim.x + threadIdx.x) >> 6;
  int lane = threadIdx.x & 63;
  if(w >= M) return;
  float2 x = *(const float2*)&X[(size_t)w*HH + 2*lane];
  float2 uu = *(const float2*)&u[2*lane];
  float p = x.x*uu.x + x.y*uu.y;
  p = wsum(p);
  if(lane==0) a[w] = p;
  if(v){
    float2 vv = *(const float2*)&v[2*lane];
    float q = x.x*vv.x + x.y*vv.y;
    q = wsum(q);
    if(lane==0) b[w] = q;
  }
}

__global__ void k_ginit(const int* __restrict__ goff, const float* __restrict__ X,
                        float* __restrict__ OUT){
  int g = (blockIdx.x*blockDim.x + threadIdx.x) >> 6;
  int lane = threadIdx.x & 63;
  if(g >= GG) return;
  int s0 = goff[g], s1 = goff[g+1];
  float hx=0.f, hy=0.f;
  for(int n=s0;n<s1;n++){
    float2 xv = *(const float2*)&X[(size_t)n*HH + 2*lane];
    hx += xv.x; hy += xv.y;
  }
  float2 o;
  o.x = fmaxf(hx, 0.f);
  o.y = fmaxf(hy, 0.f);
  *(float2*)&OUT[(size_t)g*HH + 2*lane] = o;
}

__global__ void k_weff(const float* __restrict__ lin2W, const float* __restrict__ lin2b,
                       const float* __restrict__ finW, const float* __restrict__ finb,
                       float* __restrict__ weff){
  int c = threadIdx.x;
  float s = 0.f;
  for(int j=0;j<HH;j++) s += finW[j]*lin2W[(size_t)j*HH + c];
  weff[c] = s;
  if(c==0){
    float bb = finb[0];
    for(int j=0;j<HH;j++) bb += lin2b[j]*finW[j];
    weff[HH] = bb;
  }
}

__global__ void k_final(const float* __restrict__ OUT, const float* __restrict__ weff,
                        float* __restrict__ y){
  int g = (blockIdx.x*blockDim.x + threadIdx.x) >> 6;
  int lane = threadIdx.x & 63;
  if(g >= GG) return;
  float2 ov = *(const float2*)&OUT[(size_t)g*HH + 2*lane];
  float2 wv = *(const float2*)&weff[2*lane];
  float p = ov.x*wv.x + ov.y*wv.y;
  p = wsum(p);
  if(lane==0) y[g] = sigmf(p + weff[HH]);
}

// ---------------- host ----------------
extern "C" void kernel_launch(void* const* d_in, const int* in_sizes, int n_in,
                              void* d_out, int out_size, void* d_ws, size_t ws_size,
                              hipStream_t stream){
  const float* in_x   = (const float*)d_in[0];
  const int*   eidx   = (const int*)d_in[1];
  const float* ea     = (const float*)d_in[2];
  const int*   batch  = (const int*)d_in[3];
  const float* lin1W  = (const float*)d_in[4];
  const float* lin1b  = (const float*)d_in[5];
  const float* gattl  = (const float*)d_in[6];
  const float* gattr  = (const float*)d_in[7];
  const float* glin1W = (const float*)d_in[8];
  const float* glin2W = (const float*)d_in[9];
  const float* gbias  = (const float*)d_in[10];
  const float* g0Wih  = (const float*)d_in[11];
  const float* g0Whh  = (const float*)d_in[12];
  const float* g0bih  = (const float*)d_in[13];
  const float* g0bhh  = (const float*)d_in[14];
  const float* aLinW  = (const float*)d_in[15];
  const float* aAttS  = (const float*)d_in[16];
  const float* aAttD  = (const float*)d_in[17];
  const float* aBias  = (const float*)d_in[18];
  const float* aGWih  = (const float*)d_in[19];
  const float* aGWhh  = (const float*)d_in[20];
  const float* aGbih  = (const float*)d_in[21];
  const float* aGbhh  = (const float*)d_in[22];
  const float* mLinW  = (const float*)d_in[23];
  const float* mAttS  = (const float*)d_in[24];
  const float* mAttD  = (const float*)d_in[25];
  const float* mBias  = (const float*)d_in[26];
  const float* mGWih  = (const float*)d_in[27];
  const float* mGWhh  = (const float*)d_in[28];
  const float* mGbih  = (const float*)d_in[29];
  const float* mGbhh  = (const float*)d_in[30];
  const float* lin2W  = (const float*)d_in[31];
  const float* lin2b  = (const float*)d_in[32];
  const float* finW   = (const float*)d_in[33];
  const float* finb   = (const float*)d_in[34];

  const int* esrc0 = eidx;
  const int* edst0 = eidx + EE;

  char* w = (char*)d_ws;
  size_t o = 0;
  auto alloc = [&](size_t bytes)->void*{
    void* p = w + o;
    o = (o + bytes + 255) & ~(size_t)255;
    return p;
  };
  float* X    = (float*)alloc((size_t)NN*HH*4);
  float* XB   = (float*)alloc((size_t)NN*HH*4);
  float* XS   = (float*)alloc((size_t)NN*HH*4);
  float* MSG  = (float*)alloc((size_t)NN*HH*4);
  float* XP   = (float*)alloc((size_t)NN*HH*4);
  float* ALPHA= (float*)alloc((size_t)EE*4);
  float* S1   = (float*)alloc((size_t)NN*4);
  float* S2   = (float*)alloc((size_t)NN*4);
  float* ADSTG= (float*)alloc((size_t)GG*4);
  float* OUTg = (float*)alloc((size_t)GG*HH*4);
  float* OUTb = (float*)alloc((size_t)GG*HH*4);
  float* HG   = (float*)alloc((size_t)GG*HH*4);
  float* ODg  = (float*)alloc((size_t)GG*HH*4);
  float* WEFF = (float*)alloc(256*4);
  short* cWhi = (short*)alloc((size_t)CV_TOT*2);
  short* cWlo = (short*)alloc((size_t)CV_TOT*2);
  int* zeroreg= (int*)alloc((size_t)(NN + NN + 2048)*4);
  int* deg  = zeroreg;
  int* cur  = zeroreg + NN;
  int* gcnt = zeroreg + 2*NN;
  int* eoff = (int*)alloc((size_t)(NN+1)*4);
  int* goff = (int*)alloc((size_t)(GG+1)*4);
  int* esrcS= (int*)alloc((size_t)EE*4);
  int* eperm= (int*)alloc((size_t)EE*4);

  const short* c_lin1_h = cWhi + CV_LIN1; const short* c_lin1_l = cWlo + CV_LIN1;
  const short* c_g1x_h  = cWhi + CV_G1X;  const short* c_g1x_l  = cWlo + CV_G1X;
  const short* c_g2_h   = cWhi + CV_G2;   const short* c_g2_l   = cWlo + CV_G2;
  const short* c_mol_h  = cWhi + CV_MOL;  const short* c_mol_l  = cWlo + CV_MOL;
  const short* c_g0ih_h = cWhi + CV_G0IH; const short* c_g0ih_l = cWlo + CV_G0IH;
  const short* c_g0hh_h = cWhi + CV_G0HH; const short* c_g0hh_l = cWlo + CV_G0HH;
  const short* c_mih_h  = cWhi + CV_MIH;  const short* c_mih_l  = cWlo + CV_MIH;
  const short* c_mhh_h  = cWhi + CV_MHH;  const short* c_mhh_l  = cWlo + CV_MHH;

  // ---- weight pre-split (bf16 hi/lo) ----
  k_convw2<<<(CV_TOT+255)/256, 256, 0, stream>>>(lin1W, glin1W, glin2W, aLinW, aGWih, aGWhh,
                                                 mLinW, mGWih, mGWhh, g0Wih, g0Whh, cWhi, cWlo);

  // ---- CSR build ----
  hipMemsetAsync(zeroreg, 0, (size_t)(NN + NN + 2048)*4, stream);
  k_count_edges<<<EE/256, 256, 0, stream>>>(edst0, deg);
  k_scan<<<1, 1024, 0, stream>>>(deg, eoff, NN);
  k_scatter_edges<<<EE/256, 256, 0, stream>>>(esrc0, edst0, eoff, cur, esrcS, eperm);
  k_count_graphs<<<(NN+255)/256, 256, 0, stream>>>(batch, gcnt);
  k_scan<<<1, 1024, 0, stream>>>(gcnt, goff, GG);

  const int gN = (NN + 63)/64;   // 782
  const int gG = (GG + 63)/64;   // 32

  // ---- input projection: X = leaky(x @ lin1W^T + lin1b) ----
  k_proj_mfma<1,64><<<gN, 256, 0, stream>>>(in_x, c_lin1_h, c_lin1_l, lin1b, X, NN);

  // ---- GATEConv ----
  k_dot2<<<(NN+3)/4, 256, 0, stream>>>(X, gattr, nullptr, S1, nullptr, NN);
  k_proj_mfma<0,128><<<gN, 256, 0, stream>>>(X, c_g1x_h, c_g1x_l, nullptr, XP, NN);
  k_proj_mfma<0,128><<<gN, 256, 0, stream>>>(X, c_g2_h, c_g2_l, nullptr, XS, NN);
  k_gate_alpha2<<<1024, 256, 0, stream>>>(XP, ea, esrc0, edst0, glin1W, gattl, S1, eperm, ALPHA);
  k_agg<0><<<(NN+3)/4, 256, 0, stream>>>(eoff, esrcS, ALPHA, nullptr, nullptr, XS, gbias, MSG, NN);
  k_gru_mfma<<<gN, 256, 0, stream>>>(MSG, X, c_g0ih_h, c_g0ih_l, c_g0hh_h, c_g0hh_l,
                                     g0bih, g0bhh, XB, NN);
  { float* t = X; X = XB; XB = t; }

  // ---- atom GATConv layers ----
  for(int l=0;l<2;l++){
    const short* c_a_h   = cWhi + CV_ALIN + (size_t)l*HH*HH;
    const short* c_a_l   = cWlo + CV_ALIN + (size_t)l*HH*HH;
    const short* c_aih_h = cWhi + CV_AIH + (size_t)l*3*HH*HH;
    const short* c_aih_l = cWlo + CV_AIH + (size_t)l*3*HH*HH;
    const short* c_ahh_h = cWhi + CV_AHH + (size_t)l*3*HH*HH;
    const short* c_ahh_l = cWlo + CV_AHH + (size_t)l*3*HH*HH;
    const float* asl  = aAttS + (size_t)l*HH;
    const float* adl  = aAttD + (size_t)l*HH;
    const float* bl   = aBias + (size_t)l*HH;
    const float* bi   = aGbih + (size_t)l*3*HH;
    const float* bh   = aGbhh + (size_t)l*3*HH;
    k_proj_mfma<0,128><<<gN, 256, 0, stream>>>(X, c_a_h, c_a_l, nullptr, XS, NN);
    k_dot2<<<(NN+3)/4, 256, 0, stream>>>(XS, asl, adl, S1, S2, NN);
    k_agg<1><<<(NN+3)/4, 256, 0, stream>>>(eoff, esrcS, nullptr, S1, S2, XS, bl, MSG, NN);
    k_gru_mfma<<<gN, 256, 0, stream>>>(MSG, X, c_aih_h, c_aih_l, c_ahh_h, c_ahh_l, bi, bh, XB, NN);
    { float* t = X; X = XB; XB = t; }
  }

  // ---- molecule readout ----
  k_ginit<<<(GG+3)/4, 256, 0, stream>>>(goff, X, OUTg);
  k_proj_mfma<0,128><<<gN, 256, 0, stream>>>(X, c_mol_h, c_mol_l, nullptr, XS, NN);
  k_dot2<<<(NN+3)/4, 256, 0, stream>>>(XS, mAttS, nullptr, S1, nullptr, NN);

  float* Ocur = OUTg;
  float* Onxt = OUTb;
  for(int t=0;t<3;t++){
    k_proj_mfma<0,128><<<gG, 256, 0, stream>>>(Ocur, c_mol_h, c_mol_l, nullptr, ODg, GG);
    k_dot2<<<(GG+3)/4, 256, 0, stream>>>(ODg, mAttD, nullptr, ADSTG, nullptr, GG);
    k_agg<2><<<(GG+3)/4, 256, 0, stream>>>(goff, nullptr, nullptr, S1, ADSTG, XS, mBias, HG, GG);
    k_gru_mfma<<<gG, 256, 0, stream>>>(HG, Ocur, c_mih_h, c_mih_l, c_mhh_h, c_mhh_l,
                                       mGbih, mGbhh, Onxt, GG);
    { float* tt = Ocur; Ocur = Onxt; Onxt = tt; }
  }

  // ---- fused lin2 + final ----
  k_weff<<<1, 128, 0, stream>>>(lin2W, lin2b, finW, finb, WEFF);
  k_final<<<(GG+3)/4, 256, 0, stream>>>(Ocur, WEFF, (float*)d_out);
}

// Round 6
// 1817.597 us; speedup vs baseline: 1.2168x; 1.0103x over previous
//
#include <hip/hip_runtime.h>
#include <math.h>

#define NN 50000
#define EE 800000
#define GG 2000
#define HH 128
#define FN 64
#define FE 16

typedef short bf16x8 __attribute__((ext_vector_type(8)));
typedef float f32x4  __attribute__((ext_vector_type(4)));

// ---------------- device helpers ----------------
__device__ __forceinline__ float leakyf(float v){ return v>=0.f ? v : 0.01f*v; }
__device__ __forceinline__ float eluf(float v){ return v>0.f ? v : expm1f(v); }
__device__ __forceinline__ float sigmf(float v){ return 1.f/(1.f+__expf(-v)); }
__device__ __forceinline__ float tanh_fast(float x){
  float ax = fabsf(x);
  float e = __expf(-2.f*ax);
  float t = (1.f - e)/(1.f + e);
  return x>=0.f ? t : -t;
}
__device__ __forceinline__ int rdl(int v, int l){ return __builtin_amdgcn_readlane(v, l); }
__device__ __forceinline__ float rdlf(float v, int l){
  return __int_as_float(__builtin_amdgcn_readlane(__float_as_int(v), l));
}
__device__ __forceinline__ float wsum(float v){
#pragma unroll
  for(int m=32;m>=1;m>>=1) v += __shfl_xor(v,m,64);
  return v;
}
__device__ __forceinline__ float wsum16(float v){
#pragma unroll
  for(int m=8;m>=1;m>>=1) v += __shfl_xor(v,m,64);
  return v;
}
__device__ __forceinline__ float wmax64(float v){
#pragma unroll
  for(int m=32;m>=1;m>>=1) v = fmaxf(v,__shfl_xor(v,m,64));
  return v;
}

__device__ __forceinline__ f32x4 mfma16(bf16x8 a, bf16x8 b, f32x4 c){
  return __builtin_amdgcn_mfma_f32_16x16x32_bf16(a, b, c, 0, 0, 0);
}

// split 8 consecutive fp32 into bf16 hi (truncate) + bf16 lo (truncate of residual)
__device__ __forceinline__ void splitbf8(const float* p, bf16x8 &hi, bf16x8 &lo){
  float4 u = *(const float4*)p;
  float4 v = *(const float4*)(p+4);
  float f[8] = {u.x,u.y,u.z,u.w,v.x,v.y,v.z,v.w};
#pragma unroll
  for(int i=0;i<8;i++){
    unsigned b = __float_as_uint(f[i]);
    unsigned ht = b & 0xFFFF0000u;
    hi[i] = (short)(b >> 16);
    float r = f[i] - __uint_as_float(ht);
    lo[i] = (short)(__float_as_uint(r) >> 16);
  }
}

// ---------------- weight pre-split segment map (elements) ----------------
#define CV_LIN1   0        // 128x64
#define CV_G1X    8192     // 128x128 from glin1W (ld 144, cols 0..127)
#define CV_G2     24576    // 128x128
#define CV_ALIN   40960    // 2x128x128
#define CV_MOL    73728    // 128x128
#define CV_G0IH   90112    // 384x128
#define CV_G0HH   139264
#define CV_AIH    188416   // 2x384x128
#define CV_AHH    286720
#define CV_MIH    385024
#define CV_MHH    434176
#define CV_TOT    483328

__global__ void k_convw2(const float* __restrict__ lin1W, const float* __restrict__ glin1W,
                         const float* __restrict__ glin2W, const float* __restrict__ aLinW,
                         const float* __restrict__ aGWih, const float* __restrict__ aGWhh,
                         const float* __restrict__ mLinW, const float* __restrict__ mGWih,
                         const float* __restrict__ mGWhh, const float* __restrict__ g0Wih,
                         const float* __restrict__ g0Whh,
                         short* __restrict__ hi, short* __restrict__ lo){
  int i = blockIdx.x*256 + threadIdx.x;
  if(i >= CV_TOT) return;
  float v;
  if(i < CV_G1X){            v = lin1W[i];
  } else if(i < CV_G2){      int idx = i - CV_G1X; v = glin1W[(size_t)(idx>>7)*144 + (idx&127)];
  } else if(i < CV_ALIN){    v = glin2W[i - CV_G2];
  } else if(i < CV_MOL){     v = aLinW[i - CV_ALIN];
  } else if(i < CV_G0IH){    v = mLinW[i - CV_MOL];
  } else if(i < CV_G0HH){    v = g0Wih[i - CV_G0IH];
  } else if(i < CV_AIH){     v = g0Whh[i - CV_G0HH];
  } else if(i < CV_AHH){     v = aGWih[i - CV_AIH];
  } else if(i < CV_MIH){     v = aGWhh[i - CV_AHH];
  } else if(i < CV_MHH){     v = mGWih[i - CV_MIH];
  } else {                   v = mGWhh[i - CV_MHH];
  }
  unsigned b = __float_as_uint(v);
  unsigned ht = b & 0xFFFF0000u;
  hi[i] = (short)(b >> 16);
  float r = v - __uint_as_float(ht);
  lo[i] = (short)(__float_as_uint(r) >> 16);
}

// ---------------- CSR build (fused: both edge sorts + graph counts) ----------------
__global__ void k_count_all(const int* __restrict__ esrc, const int* __restrict__ edst,
                            const int* __restrict__ batch,
                            int* __restrict__ degd, int* __restrict__ degs,
                            int* __restrict__ gcnt){
  int i = blockIdx.x*256 + threadIdx.x;
  if(i < EE){
    atomicAdd(&degd[edst[i]], 1);
    atomicAdd(&degs[esrc[i]], 1);
  }
  if(i < NN) atomicAdd(&gcnt[batch[i]], 1);
}

__global__ void k_scan3(const int* __restrict__ degd, const int* __restrict__ degs,
                        const int* __restrict__ gcnt,
                        int* __restrict__ eoff, int* __restrict__ soff, int* __restrict__ goff){
  __shared__ int part[1024];
  const int* cnt; int* off; int n;
  if(blockIdx.x == 0){ cnt = degd; off = eoff; n = NN; }
  else if(blockIdx.x == 1){ cnt = degs; off = soff; n = NN; }
  else { cnt = gcnt; off = goff; n = GG; }
  int t = threadIdx.x;
  int C = (n + 1023) >> 10;
  int lo = t*C, hic = min(lo + C, n);
  int s = 0;
  for(int i=lo;i<hic;i++) s += cnt[i];
  part[t] = s;
  __syncthreads();
  for(int o=1;o<1024;o<<=1){
    int v = (t>=o) ? part[t-o] : 0;
    __syncthreads();
    part[t] += v;
    __syncthreads();
  }
  int base = part[t] - s;
  int run = base;
  for(int i=lo;i<hic;i++){ run += cnt[i]; off[i+1] = run; }
  if(t==0) off[0] = 0;
}

__global__ void k_scatter2(const int* __restrict__ esrc, const int* __restrict__ edst,
                           const int* __restrict__ eoff, const int* __restrict__ soff,
                           int* __restrict__ curd, int* __restrict__ curs,
                           int* __restrict__ esrcS, int* __restrict__ eperm,
                           int* __restrict__ eord){
  int e = blockIdx.x*256 + threadIdx.x;
  if(e < EE){
    int d = edst[e];
    int pos = eoff[d] + atomicAdd(&curd[d], 1);
    esrcS[pos] = esrc[e];
    eperm[e] = pos;
    int s = esrc[e];
    int pos2 = soff[s] + atomicAdd(&curs[s], 1);
    eord[pos2] = e;
  }
}

// ---------------- MFMA projection + fused row-dots ----------------
// C[M,128] = act(A[M,K] @ W^T (+bias)); optional douta[m]=C[m]·u, doutb[m]=C[m]·v
// A-frag: row=lane&15, k=(lane>>4)*8+i.  C/D: col=lane&15, row=(lane>>4)*4+reg.
template<int ACT, int K, int NDOT>
__global__ __launch_bounds__(256) void k_proj_mfma(const float* __restrict__ A,
                                                   const short* __restrict__ Whi,
                                                   const short* __restrict__ Wlo,
                                                   const float* __restrict__ bias,
                                                   float* __restrict__ C, int M,
                                                   const float* __restrict__ u,
                                                   const float* __restrict__ v,
                                                   float* __restrict__ douta,
                                                   float* __restrict__ doutb){
  const int wave = threadIdx.x >> 6, lane = threadIdx.x & 63;
  const int m0 = blockIdx.x*64 + wave*16;
  const int lr = lane & 15, kg = lane >> 4;
  f32x4 acc[8];
#pragma unroll
  for(int t=0;t<8;t++) acc[t] = (f32x4){0.f,0.f,0.f,0.f};

  int arow = m0 + lr;
  int ar = arow < M ? arow : (M-1);

#pragma unroll
  for(int ks=0;ks<K;ks+=32){
    const int kb = ks + kg*8;
    bf16x8 ahi, alo;
    splitbf8(&A[(size_t)ar*K + kb], ahi, alo);
#pragma unroll
    for(int t=0;t<8;t++){
      const bf16x8 bh = *(const bf16x8*)&Whi[(size_t)(t*16+lr)*K + kb];
      const bf16x8 bl = *(const bf16x8*)&Wlo[(size_t)(t*16+lr)*K + kb];
      acc[t] = mfma16(ahi, bh, acc[t]);
      acc[t] = mfma16(ahi, bl, acc[t]);
      acc[t] = mfma16(alo, bh, acc[t]);
    }
  }

  float p1[4] = {0.f,0.f,0.f,0.f};
  float p2[4] = {0.f,0.f,0.f,0.f};
#pragma unroll
  for(int t=0;t<8;t++){
    int c = t*16 + lr;
    float ut = (NDOT>=1) ? u[c] : 0.f;
    float vt = (NDOT>=2) ? v[c] : 0.f;
#pragma unroll
    for(int r=0;r<4;r++){
      int m = m0 + kg*4 + r;
      float val = acc[t][r];
      if(ACT==1) val = leakyf(val + bias[c]);
      if(m < M) C[(size_t)m*HH + c] = val;
      if(NDOT>=1) p1[r] += val*ut;
      if(NDOT>=2) p2[r] += val*vt;
    }
  }
  if(NDOT>=1){
#pragma unroll
    for(int r=0;r<4;r++){
      float s1 = wsum16(p1[r]);
      int m = m0 + kg*4 + r;
      if(lr==0 && m < M) douta[m] = s1;
      if(NDOT>=2){
        float s2 = wsum16(p2[r]);
        if(lr==0 && m < M) doutb[m] = s2;
      }
    }
  }
}

// ---------------- fused MFMA GRUCell (anti-spill v2, r5-verified) ----------------
__global__ __launch_bounds__(256) void k_gru_mfma(const float* __restrict__ MSG,
                                                  const float* __restrict__ X,
                                                  const short* __restrict__ WIhi,
                                                  const short* __restrict__ WIlo,
                                                  const short* __restrict__ WHhi,
                                                  const short* __restrict__ WHlo,
                                                  const float* __restrict__ bih,
                                                  const float* __restrict__ bhh,
                                                  float* __restrict__ XOUT, int M){
  const int wave = threadIdx.x >> 6, lane = threadIdx.x & 63;
  const int m0 = blockIdx.x*64 + wave*16;
  const int lr = lane & 15, kg = lane >> 4;
  int arow = m0 + lr;
  int ar = arow < M ? arow : (M-1);

  bf16x8 mh[4], ml[4], xh[4], xl[4];
#pragma unroll
  for(int ks=0;ks<4;ks++){
    splitbf8(&MSG[(size_t)ar*HH + ks*32 + kg*8], mh[ks], ml[ks]);
    splitbf8(&X  [(size_t)ar*HH + ks*32 + kg*8], xh[ks], xl[ks]);
  }

#pragma unroll 1
  for(int t=0;t<8;t++){
    f32x4 aIr = (f32x4){0.f,0.f,0.f,0.f}, aIz = aIr, aIn = aIr;
    f32x4 aHr = aIr, aHz = aIr, aHn = aIr;
    const size_t rbase = (size_t)(t*16 + lr)*HH;
#pragma unroll
    for(int ks=0;ks<4;ks++){
      const int kb = ks*32 + kg*8;
      const size_t o0 = rbase + kb;
      const size_t o1 = o0 + (size_t)128*HH;
      const size_t o2 = o1 + (size_t)128*HH;
      bf16x8 bh_, bl_;
      bh_ = *(const bf16x8*)&WIhi[o0]; bl_ = *(const bf16x8*)&WIlo[o0];
      aIr = mfma16(mh[ks], bh_, aIr); aIr = mfma16(mh[ks], bl_, aIr); aIr = mfma16(ml[ks], bh_, aIr);
      bh_ = *(const bf16x8*)&WIhi[o1]; bl_ = *(const bf16x8*)&WIlo[o1];
      aIz = mfma16(mh[ks], bh_, aIz); aIz = mfma16(mh[ks], bl_, aIz); aIz = mfma16(ml[ks], bh_, aIz);
      bh_ = *(const bf16x8*)&WIhi[o2]; bl_ = *(const bf16x8*)&WIlo[o2];
      aIn = mfma16(mh[ks], bh_, aIn); aIn = mfma16(mh[ks], bl_, aIn); aIn = mfma16(ml[ks], bh_, aIn);
      bh_ = *(const bf16x8*)&WHhi[o0]; bl_ = *(const bf16x8*)&WHlo[o0];
      aHr = mfma16(xh[ks], bh_, aHr); aHr = mfma16(xh[ks], bl_, aHr); aHr = mfma16(xl[ks], bh_, aHr);
      bh_ = *(const bf16x8*)&WHhi[o1]; bl_ = *(const bf16x8*)&WHlo[o1];
      aHz = mfma16(xh[ks], bh_, aHz); aHz = mfma16(xh[ks], bl_, aHz); aHz = mfma16(xl[ks], bh_, aHz);
      bh_ = *(const bf16x8*)&WHhi[o2]; bl_ = *(const bf16x8*)&WHlo[o2];
      aHn = mfma16(xh[ks], bh_, aHn); aHn = mfma16(xh[ks], bl_, aHn); aHn = mfma16(xl[ks], bh_, aHn);
    }
    const int c = t*16 + lr;
    const float bir = bih[c], biz = bih[c+HH], bin = bih[c+2*HH];
    const float bhr = bhh[c], bhz = bhh[c+HH], bhn = bhh[c+2*HH];
#pragma unroll
    for(int r=0;r<4;r++){
      int mm = m0 + kg*4 + r;
      if(mm < M){
        float ir = aIr[r]+bir, iz = aIz[r]+biz, in_ = aIn[r]+bin;
        float hr = aHr[r]+bhr, hz = aHz[r]+bhz, hn = aHn[r]+bhn;
        float rr = sigmf(ir + hr);
        float z  = sigmf(iz + hz);
        float ng = tanh_fast(in_ + rr*hn);
        float hp = X[(size_t)mm*HH + c];
        XOUT[(size_t)mm*HH + c] = fmaxf((1.f - z)*ng + z*hp, 0.f);
      }
    }
  }
}

// ---------------- GATEConv edge alpha v3: src-sorted, lane-parallel, no cross-lane ----------------
// lane owns one edge (src-sorted order -> XP row L1 reuse, avg degree 16).
// W1e [128][16] + attl in LDS (uniform-address broadcast reads, conflict-free).
__global__ __launch_bounds__(256) void k_gate_alpha3(const float* __restrict__ XP,
                                                     const float* __restrict__ EA,
                                                     const int* __restrict__ esrc,
                                                     const int* __restrict__ edst,
                                                     const float* __restrict__ W1,
                                                     const float* __restrict__ attl,
                                                     const float* __restrict__ RD,
                                                     const int* __restrict__ eperm,
                                                     const int* __restrict__ eord,
                                                     float* __restrict__ ALPHA){
  __shared__ float W1E[128*16];
  __shared__ float ATTL[128];
  const int tid = threadIdx.x;
#pragma unroll
  for(int q=0;q<8;q++){
    int idx = tid*8 + q;            // 0..2047
    int c = idx >> 4, f = idx & 15;
    W1E[idx] = W1[(size_t)c*144 + 128 + f];
  }
  if(tid < 128) ATTL[tid] = attl[tid];
  __syncthreads();

  const int p = blockIdx.x*256 + tid;   // grid sized exactly EE/256
  const int eo = eord[p];
  const int s  = esrc[eo];
  const int d  = edst[eo];
  const int pd = eperm[eo];

  float ea[16];
  {
    const float4* g = (const float4*)&EA[(size_t)eo*FE];
    float4 v0=g[0], v1=g[1], v2=g[2], v3=g[3];
    ea[0]=v0.x;ea[1]=v0.y;ea[2]=v0.z;ea[3]=v0.w;
    ea[4]=v1.x;ea[5]=v1.y;ea[6]=v1.z;ea[7]=v1.w;
    ea[8]=v2.x;ea[9]=v2.y;ea[10]=v2.z;ea[11]=v2.w;
    ea[12]=v3.x;ea[13]=v3.y;ea[14]=v3.z;ea[15]=v3.w;
  }

  float acc = 0.f;
#pragma unroll 4
  for(int c0=0;c0<HH;c0+=4){
    float4 xp = *(const float4*)&XP[(size_t)s*HH + c0];
    float xpv[4] = {xp.x, xp.y, xp.z, xp.w};
#pragma unroll
    for(int cc=0;cc<4;cc++){
      const float* wr = &W1E[(c0+cc)*16];
      float eaw = 0.f;
#pragma unroll
      for(int f=0;f<16;f++) eaw += ea[f]*wr[f];
      acc += leakyf(xpv[cc] + eaw) * ATTL[c0+cc];
    }
  }
  ALPHA[pd] = leakyf(acc + RD[d]);
}

// ---------------- segment softmax -> normalized edge weights (scalar only) ----------------
// MODE 0: alpha = AIN[i] (in-place AIN==WOUT is safe)
// MODE 1: alpha = leaky(A1[items[i]] + A2[seg])
// MODE 2: alpha = leaky(A1[i] + A2[seg])
template<int MODE>
__global__ void k_softmaxw(const int* __restrict__ off, const int* __restrict__ items,
                           const float* __restrict__ AIN, const float* __restrict__ A1,
                           const float* __restrict__ A2, float* __restrict__ WOUT, int nseg){
  int w = (blockIdx.x*blockDim.x + threadIdx.x) >> 6;
  int lane = threadIdx.x & 63;
  if(w >= nseg) return;
  int s0 = off[w], s1 = off[w+1];
  float a2 = (MODE==0) ? 0.f : A2[w];

  float m = -INFINITY;
  for(int i=s0+lane;i<s1;i+=64){
    float a;
    if(MODE==0) a = AIN[i];
    else if(MODE==1) a = leakyf(A1[items[i]] + a2);
    else a = leakyf(A1[i] + a2);
    m = fmaxf(m, a);
  }
  m = wmax64(m);

  float s = 0.f;
  for(int i=s0+lane;i<s1;i+=64){
    float a;
    if(MODE==0) a = AIN[i];
    else if(MODE==1) a = leakyf(A1[items[i]] + a2);
    else a = leakyf(A1[i] + a2);
    s += __expf(a - m);
  }
  s = wsum(s);
  float inv = 1.f/(s + 1e-16f);

  for(int i=s0+lane;i<s1;i+=64){
    float a;
    if(MODE==0) a = AIN[i];
    else if(MODE==1) a = leakyf(A1[items[i]] + a2);
    else a = leakyf(A1[i] + a2);
    WOUT[i] = __expf(a - m)*inv;
  }
}

// ---------------- weighted row gather: OUT[w] = elu(sum_i W[i]*XSrc[it_i] + bias) ----------------
__global__ void k_gather(const int* __restrict__ off, const int* __restrict__ items,
                         const float* __restrict__ W, const float* __restrict__ XSrc,
                         const float* __restrict__ bias, float* __restrict__ OUT, int nseg){
  int w = (blockIdx.x*blockDim.x + threadIdx.x) >> 6;
  int lane = threadIdx.x & 63;
  if(w >= nseg) return;
  int s0 = off[w], s1 = off[w+1];
  float hx = 0.f, hy = 0.f;

  for(int c0=s0;c0<s1;c0+=64){
    int n = min(64, s1-c0);
    int it = 0; float wg = 0.f;
    if(lane < n){
      int i = c0 + lane;
      it = items ? items[i] : i;
      wg = W[i];
    }
#pragma unroll 16
    for(int j=0;j<n;j++){
      int itj = rdl(it, j);
      float wj = rdlf(wg, j);
      float2 xv = *(const float2*)&XSrc[(size_t)itj*HH + 2*lane];
      hx += wj*xv.x;
      hy += wj*xv.y;
    }
  }
  float2 bv = *(const float2*)&bias[2*lane];
  float2 o;
  o.x = eluf(hx + bv.x);
  o.y = eluf(hy + bv.y);
  *(float2*)&OUT[(size_t)w*HH + 2*lane] = o;
}

// ---------------- small per-row kernels ----------------
__global__ void k_dot2(const float* __restrict__ X, const float* __restrict__ u,
                       float* __restrict__ a, int M){
  int w = (blockIdx.x*blockDim.x + threadIdx.x) >> 6;
  int lane = threadIdx.x & 63;
  if(w >= M) return;
  float2 x = *(const float2*)&X[(size_t)w*HH + 2*lane];
  float2 uu = *(const float2*)&u[2*lane];
  float p = x.x*uu.x + x.y*uu.y;
  p = wsum(p);
  if(lane==0) a[w] = p;
}

__global__ void k_ginit(const int* __restrict__ goff, const float* __restrict__ X,
                        float* __restrict__ OUT){
  int g = (blockIdx.x*blockDim.x + threadIdx.x) >> 6;
  int lane = threadIdx.x & 63;
  if(g >= GG) return;
  int s0 = goff[g], s1 = goff[g+1];
  float hx=0.f, hy=0.f;
  for(int n=s0;n<s1;n++){
    float2 xv = *(const float2*)&X[(size_t)n*HH + 2*lane];
    hx += xv.x; hy += xv.y;
  }
  float2 o;
  o.x = fmaxf(hx, 0.f);
  o.y = fmaxf(hy, 0.f);
  *(float2*)&OUT[(size_t)g*HH + 2*lane] = o;
}

// weff[c] = finW·lin2W[:,c]; weff[128] = lin2b·finW + finb; weff[256+c] = mAttD·mLinW[:,c]
__global__ void k_weff(const float* __restrict__ lin2W, const float* __restrict__ lin2b,
                       const float* __restrict__ finW, const float* __restrict__ finb,
                       const float* __restrict__ mLinW, const float* __restrict__ mAttD,
                       float* __restrict__ weff){
  int c = threadIdx.x;
  float s = 0.f, q = 0.f;
  for(int j=0;j<HH;j++){
    s += finW[j]*lin2W[(size_t)j*HH + c];
    q += mAttD[j]*mLinW[(size_t)j*HH + c];
  }
  weff[c] = s;
  weff[256 + c] = q;
  if(c==0){
    float bb = finb[0];
    for(int j=0;j<HH;j++) bb += lin2b[j]*finW[j];
    weff[HH] = bb;
  }
}

__global__ void k_final(const float* __restrict__ OUT, const float* __restrict__ weff,
                        float* __restrict__ y){
  int g = (blockIdx.x*blockDim.x + threadIdx.x) >> 6;
  int lane = threadIdx.x & 63;
  if(g >= GG) return;
  float2 ov = *(const float2*)&OUT[(size_t)g*HH + 2*lane];
  float2 wv = *(const float2*)&weff[2*lane];
  float p = ov.x*wv.x + ov.y*wv.y;
  p = wsum(p);
  if(lane==0) y[g] = sigmf(p + weff[HH]);
}

// ---------------- host ----------------
extern "C" void kernel_launch(void* const* d_in, const int* in_sizes, int n_in,
                              void* d_out, int out_size, void* d_ws, size_t ws_size,
                              hipStream_t stream){
  const float* in_x   = (const float*)d_in[0];
  const int*   eidx   = (const int*)d_in[1];
  const float* ea     = (const float*)d_in[2];
  const int*   batch  = (const int*)d_in[3];
  const float* lin1W  = (const float*)d_in[4];
  const float* lin1b  = (const float*)d_in[5];
  const float* gattl  = (const float*)d_in[6];
  const float* gattr  = (const float*)d_in[7];
  const float* glin1W = (const float*)d_in[8];
  const float* glin2W = (const float*)d_in[9];
  const float* gbias  = (const float*)d_in[10];
  const float* g0Wih  = (const float*)d_in[11];
  const float* g0Whh  = (const float*)d_in[12];
  const float* g0bih  = (const float*)d_in[13];
  const float* g0bhh  = (const float*)d_in[14];
  const float* aLinW  = (const float*)d_in[15];
  const float* aAttS  = (const float*)d_in[16];
  const float* aAttD  = (const float*)d_in[17];
  const float* aBias  = (const float*)d_in[18];
  const float* aGWih  = (const float*)d_in[19];
  const float* aGWhh  = (const float*)d_in[20];
  const float* aGbih  = (const float*)d_in[21];
  const float* aGbhh  = (const float*)d_in[22];
  const float* mLinW  = (const float*)d_in[23];
  const float* mAttS  = (const float*)d_in[24];
  const float* mAttD  = (const float*)d_in[25];
  const float* mBias  = (const float*)d_in[26];
  const float* mGWih  = (const float*)d_in[27];
  const float* mGWhh  = (const float*)d_in[28];
  const float* mGbih  = (const float*)d_in[29];
  const float* mGbhh  = (const float*)d_in[30];
  const float* lin2W  = (const float*)d_in[31];
  const float* lin2b  = (const float*)d_in[32];
  const float* finW   = (const float*)d_in[33];
  const float* finb   = (const float*)d_in[34];

  const int* esrc0 = eidx;
  const int* edst0 = eidx + EE;

  char* w = (char*)d_ws;
  size_t o = 0;
  auto alloc = [&](size_t bytes)->void*{
    void* p = w + o;
    o = (o + bytes + 255) & ~(size_t)255;
    return p;
  };
  float* X    = (float*)alloc((size_t)NN*HH*4);
  float* XB   = (float*)alloc((size_t)NN*HH*4);
  float* XS   = (float*)alloc((size_t)NN*HH*4);
  float* MSG  = (float*)alloc((size_t)NN*HH*4);
  float* XP   = (float*)alloc((size_t)NN*HH*4);
  float* ALPHA= (float*)alloc((size_t)EE*4);     // also reused as WEIGHT everywhere
  float* S1   = (float*)alloc((size_t)NN*4);
  float* S2   = (float*)alloc((size_t)NN*4);
  float* ADSTG= (float*)alloc((size_t)GG*4);
  float* OUTg = (float*)alloc((size_t)GG*HH*4);
  float* OUTb = (float*)alloc((size_t)GG*HH*4);
  float* HG   = (float*)alloc((size_t)GG*HH*4);
  float* WEFF = (float*)alloc(512*4);
  short* cWhi = (short*)alloc((size_t)CV_TOT*2);
  short* cWlo = (short*)alloc((size_t)CV_TOT*2);
  int* zeroreg= (int*)alloc((size_t)(4*NN + 2048)*4);  // degd|degs|curd|curs|gcnt
  int* degd = zeroreg;
  int* degs = zeroreg + NN;
  int* curd = zeroreg + 2*NN;
  int* curs = zeroreg + 3*NN;
  int* gcnt = zeroreg + 4*NN;
  int* eoff = (int*)alloc((size_t)(NN+1)*4);
  int* soff = (int*)alloc((size_t)(NN+1)*4);
  int* goff = (int*)alloc((size_t)(GG+1)*4);
  int* esrcS= (int*)alloc((size_t)EE*4);
  int* eperm= (int*)alloc((size_t)EE*4);
  int* eord = (int*)alloc((size_t)EE*4);

  const short* c_lin1_h = cWhi + CV_LIN1; const short* c_lin1_l = cWlo + CV_LIN1;
  const short* c_g1x_h  = cWhi + CV_G1X;  const short* c_g1x_l  = cWlo + CV_G1X;
  const short* c_g2_h   = cWhi + CV_G2;   const short* c_g2_l   = cWlo + CV_G2;
  const short* c_mol_h  = cWhi + CV_MOL;  const short* c_mol_l  = cWlo + CV_MOL;
  const short* c_g0ih_h = cWhi + CV_G0IH; const short* c_g0ih_l = cWlo + CV_G0IH;
  const short* c_g0hh_h = cWhi + CV_G0HH; const short* c_g0hh_l = cWlo + CV_G0HH;
  const short* c_mih_h  = cWhi + CV_MIH;  const short* c_mih_l  = cWlo + CV_MIH;
  const short* c_mhh_h  = cWhi + CV_MHH;  const short* c_mhh_l  = cWlo + CV_MHH;

  // ---- weight pre-split + fused final-layer vectors ----
  k_convw2<<<(CV_TOT+255)/256, 256, 0, stream>>>(lin1W, glin1W, glin2W, aLinW, aGWih, aGWhh,
                                                 mLinW, mGWih, mGWhh, g0Wih, g0Whh, cWhi, cWlo);
  k_weff<<<1, 128, 0, stream>>>(lin2W, lin2b, finW, finb, mLinW, mAttD, WEFF);

  // ---- CSR build (dst-sorted + src-sorted + graph offsets) ----
  hipMemsetAsync(zeroreg, 0, (size_t)(4*NN + 2048)*4, stream);
  k_count_all<<<EE/256, 256, 0, stream>>>(esrc0, edst0, batch, degd, degs, gcnt);
  k_scan3<<<3, 1024, 0, stream>>>(degd, degs, gcnt, eoff, soff, goff);
  k_scatter2<<<EE/256, 256, 0, stream>>>(esrc0, edst0, eoff, soff, curd, curs, esrcS, eperm, eord);

  const int gN = (NN + 63)/64;   // 782
  const int gG = (GG + 63)/64;   // 32

  // ---- input projection (+ fused S1 = X·gattr) ----
  k_proj_mfma<1,64,1><<<gN, 256, 0, stream>>>(in_x, c_lin1_h, c_lin1_l, lin1b, X, NN,
                                              gattr, nullptr, S1, nullptr);

  // ---- GATEConv ----
  k_proj_mfma<0,128,0><<<gN, 256, 0, stream>>>(X, c_g1x_h, c_g1x_l, nullptr, XP, NN,
                                               nullptr, nullptr, nullptr, nullptr);
  k_proj_mfma<0,128,0><<<gN, 256, 0, stream>>>(X, c_g2_h, c_g2_l, nullptr, XS, NN,
                                               nullptr, nullptr, nullptr, nullptr);
  k_gate_alpha3<<<EE/256, 256, 0, stream>>>(XP, ea, esrc0, edst0, glin1W, gattl, S1,
                                            eperm, eord, ALPHA);
  k_softmaxw<0><<<(NN+3)/4, 256, 0, stream>>>(eoff, nullptr, ALPHA, nullptr, nullptr, ALPHA, NN);
  k_gather<<<(NN+3)/4, 256, 0, stream>>>(eoff, esrcS, ALPHA, XS, gbias, MSG, NN);
  k_gru_mfma<<<gN, 256, 0, stream>>>(MSG, X, c_g0ih_h, c_g0ih_l, c_g0hh_h, c_g0hh_l,
                                     g0bih, g0bhh, XB, NN);
  { float* t = X; X = XB; XB = t; }

  // ---- atom GATConv layers ----
  for(int l=0;l<2;l++){
    const short* c_a_h   = cWhi + CV_ALIN + (size_t)l*HH*HH;
    const short* c_a_l   = cWlo + CV_ALIN + (size_t)l*HH*HH;
    const short* c_aih_h = cWhi + CV_AIH + (size_t)l*3*HH*HH;
    const short* c_aih_l = cWlo + CV_AIH + (size_t)l*3*HH*HH;
    const short* c_ahh_h = cWhi + CV_AHH + (size_t)l*3*HH*HH;
    const short* c_ahh_l = cWlo + CV_AHH + (size_t)l*3*HH*HH;
    const float* asl  = aAttS + (size_t)l*HH;
    const float* adl  = aAttD + (size_t)l*HH;
    const float* bl   = aBias + (size_t)l*HH;
    const float* bi   = aGbih + (size_t)l*3*HH;
    const float* bh   = aGbhh + (size_t)l*3*HH;
    k_proj_mfma<0,128,2><<<gN, 256, 0, stream>>>(X, c_a_h, c_a_l, nullptr, XS, NN,
                                                 asl, adl, S1, S2);
    k_softmaxw<1><<<(NN+3)/4, 256, 0, stream>>>(eoff, esrcS, nullptr, S1, S2, ALPHA, NN);
    k_gather<<<(NN+3)/4, 256, 0, stream>>>(eoff, esrcS, ALPHA, XS, bl, MSG, NN);
    k_gru_mfma<<<gN, 256, 0, stream>>>(MSG, X, c_aih_h, c_aih_l, c_ahh_h, c_ahh_l, bi, bh, XB, NN);
    { float* t = X; X = XB; XB = t; }
  }

  // ---- molecule readout ----
  k_ginit<<<(GG+3)/4, 256, 0, stream>>>(goff, X, OUTg);
  k_proj_mfma<0,128,1><<<gN, 256, 0, stream>>>(X, c_mol_h, c_mol_l, nullptr, XS, NN,
                                               mAttS, nullptr, S1, nullptr);

  float* Ocur = OUTg;
  float* Onxt = OUTb;
  for(int t=0;t<3;t++){
    // ADSTG[g] = Ocur[g]·(mLinW^T mAttD)   [od@mAttD collapsed algebraically]
    k_dot2<<<(GG+3)/4, 256, 0, stream>>>(Ocur, WEFF+256, ADSTG, GG);
    k_softmaxw<2><<<(GG+3)/4, 256, 0, stream>>>(goff, nullptr, nullptr, S1, ADSTG, ALPHA, GG);
    k_gather<<<(GG+3)/4, 256, 0, stream>>>(goff, nullptr, ALPHA, XS, mBias, HG, GG);
    k_gru_mfma<<<gG, 256, 0, stream>>>(HG, Ocur, c_mih_h, c_mih_l, c_mhh_h, c_mhh_l,
                                       mGbih, mGbhh, Onxt, GG);
    { float* tt = Ocur; Ocur = Onxt; Onxt = tt; }
  }

  // ---- fused lin2 + final ----
  k_final<<<(GG+3)/4, 256, 0, stream>>>(Ocur, WEFF, (float*)d_out);
}

// Round 7
// 1295.762 us; speedup vs baseline: 1.7068x; 1.4027x over previous
//
#include <hip/hip_runtime.h>
#include <math.h>

#define NN 50000
#define EE 800000
#define GG 2000
#define HH 128
#define FN 64
#define FE 16

typedef short bf16x8 __attribute__((ext_vector_type(8)));
typedef float f32x4  __attribute__((ext_vector_type(4)));

// ---------------- device helpers ----------------
__device__ __forceinline__ float leakyf(float v){ return v>=0.f ? v : 0.01f*v; }
__device__ __forceinline__ float eluf(float v){ return v>0.f ? v : expm1f(v); }
__device__ __forceinline__ float sigmf(float v){ return 1.f/(1.f+__expf(-v)); }
__device__ __forceinline__ float tanh_fast(float x){
  float ax = fabsf(x);
  float e = __expf(-2.f*ax);
  float t = (1.f - e)/(1.f + e);
  return x>=0.f ? t : -t;
}
__device__ __forceinline__ int rdl(int v, int l){ return __builtin_amdgcn_readlane(v, l); }
__device__ __forceinline__ float rdlf(float v, int l){
  return __int_as_float(__builtin_amdgcn_readlane(__float_as_int(v), l));
}
__device__ __forceinline__ float wsum(float v){
#pragma unroll
  for(int m=32;m>=1;m>>=1) v += __shfl_xor(v,m,64);
  return v;
}
__device__ __forceinline__ float wsum16(float v){
#pragma unroll
  for(int m=8;m>=1;m>>=1) v += __shfl_xor(v,m,64);
  return v;
}
__device__ __forceinline__ float wmax64(float v){
#pragma unroll
  for(int m=32;m>=1;m>>=1) v = fmaxf(v,__shfl_xor(v,m,64));
  return v;
}

__device__ __forceinline__ f32x4 mfma16(bf16x8 a, bf16x8 b, f32x4 c){
  return __builtin_amdgcn_mfma_f32_16x16x32_bf16(a, b, c, 0, 0, 0);
}

// split 8 consecutive fp32 into bf16 hi (truncate) + bf16 lo (truncate of residual)
__device__ __forceinline__ void splitbf8(const float* p, bf16x8 &hi, bf16x8 &lo){
  float4 u = *(const float4*)p;
  float4 v = *(const float4*)(p+4);
  float f[8] = {u.x,u.y,u.z,u.w,v.x,v.y,v.z,v.w};
#pragma unroll
  for(int i=0;i<8;i++){
    unsigned b = __float_as_uint(f[i]);
    unsigned ht = b & 0xFFFF0000u;
    hi[i] = (short)(b >> 16);
    float r = f[i] - __uint_as_float(ht);
    lo[i] = (short)(__float_as_uint(r) >> 16);
  }
}

// ---------------- weight pre-split segment map (elements) ----------------
#define CV_LIN1   0        // 128x64
#define CV_G1X    8192     // 128x128 from glin1W (ld 144, cols 0..127)
#define CV_G2     24576    // 128x128
#define CV_ALIN   40960    // 2x128x128
#define CV_MOL    73728    // 128x128
#define CV_G0IH   90112    // 384x128
#define CV_G0HH   139264
#define CV_AIH    188416   // 2x384x128
#define CV_AHH    286720
#define CV_MIH    385024
#define CV_MHH    434176
#define CV_TOT    483328

__global__ void k_convw2(const float* __restrict__ lin1W, const float* __restrict__ glin1W,
                         const float* __restrict__ glin2W, const float* __restrict__ aLinW,
                         const float* __restrict__ aGWih, const float* __restrict__ aGWhh,
                         const float* __restrict__ mLinW, const float* __restrict__ mGWih,
                         const float* __restrict__ mGWhh, const float* __restrict__ g0Wih,
                         const float* __restrict__ g0Whh,
                         short* __restrict__ hi, short* __restrict__ lo){
  int i = blockIdx.x*256 + threadIdx.x;
  if(i >= CV_TOT) return;
  float v;
  if(i < CV_G1X){            v = lin1W[i];
  } else if(i < CV_G2){      int idx = i - CV_G1X; v = glin1W[(size_t)(idx>>7)*144 + (idx&127)];
  } else if(i < CV_ALIN){    v = glin2W[i - CV_G2];
  } else if(i < CV_MOL){     v = aLinW[i - CV_ALIN];
  } else if(i < CV_G0IH){    v = mLinW[i - CV_MOL];
  } else if(i < CV_G0HH){    v = g0Wih[i - CV_G0IH];
  } else if(i < CV_AIH){     v = g0Whh[i - CV_G0HH];
  } else if(i < CV_AHH){     v = aGWih[i - CV_AIH];
  } else if(i < CV_MIH){     v = aGWhh[i - CV_AHH];
  } else if(i < CV_MHH){     v = mGWih[i - CV_MIH];
  } else {                   v = mGWhh[i - CV_MHH];
  }
  unsigned b = __float_as_uint(v);
  unsigned ht = b & 0xFFFF0000u;
  hi[i] = (short)(b >> 16);
  float r = v - __uint_as_float(ht);
  lo[i] = (short)(__float_as_uint(r) >> 16);
}

// ---------------- CSR build (fused: both edge sorts + graph counts) ----------------
__global__ void k_count_all(const int* __restrict__ esrc, const int* __restrict__ edst,
                            const int* __restrict__ batch,
                            int* __restrict__ degd, int* __restrict__ degs,
                            int* __restrict__ gcnt){
  int i = blockIdx.x*256 + threadIdx.x;
  if(i < EE){
    atomicAdd(&degd[edst[i]], 1);
    atomicAdd(&degs[esrc[i]], 1);
  }
  if(i < NN) atomicAdd(&gcnt[batch[i]], 1);
}

__global__ void k_scan3(const int* __restrict__ degd, const int* __restrict__ degs,
                        const int* __restrict__ gcnt,
                        int* __restrict__ eoff, int* __restrict__ soff, int* __restrict__ goff){
  __shared__ int part[1024];
  const int* cnt; int* off; int n;
  if(blockIdx.x == 0){ cnt = degd; off = eoff; n = NN; }
  else if(blockIdx.x == 1){ cnt = degs; off = soff; n = NN; }
  else { cnt = gcnt; off = goff; n = GG; }
  int t = threadIdx.x;
  int C = (n + 1023) >> 10;
  int lo = t*C, hic = min(lo + C, n);
  int s = 0;
  for(int i=lo;i<hic;i++) s += cnt[i];
  part[t] = s;
  __syncthreads();
  for(int o=1;o<1024;o<<=1){
    int v = (t>=o) ? part[t-o] : 0;
    __syncthreads();
    part[t] += v;
    __syncthreads();
  }
  int base = part[t] - s;
  int run = base;
  for(int i=lo;i<hic;i++){ run += cnt[i]; off[i+1] = run; }
  if(t==0) off[0] = 0;
}

__global__ void k_scatter2(const int* __restrict__ esrc, const int* __restrict__ edst,
                           const int* __restrict__ eoff, const int* __restrict__ soff,
                           int* __restrict__ curd, int* __restrict__ curs,
                           int* __restrict__ esrcS, int* __restrict__ eperm,
                           int* __restrict__ eord){
  int e = blockIdx.x*256 + threadIdx.x;
  if(e < EE){
    int d = edst[e];
    int pos = eoff[d] + atomicAdd(&curd[d], 1);
    esrcS[pos] = esrc[e];
    eperm[e] = pos;
    int s = esrc[e];
    int pos2 = soff[s] + atomicAdd(&curs[s], 1);
    eord[pos2] = e;
  }
}

// ---------------- MFMA projection + fused row-dots ----------------
template<int ACT, int K, int NDOT>
__global__ __launch_bounds__(256) void k_proj_mfma(const float* __restrict__ A,
                                                   const short* __restrict__ Whi,
                                                   const short* __restrict__ Wlo,
                                                   const float* __restrict__ bias,
                                                   float* __restrict__ C, int M,
                                                   const float* __restrict__ u,
                                                   const float* __restrict__ v,
                                                   float* __restrict__ douta,
                                                   float* __restrict__ doutb){
  const int wave = threadIdx.x >> 6, lane = threadIdx.x & 63;
  const int m0 = blockIdx.x*64 + wave*16;
  const int lr = lane & 15, kg = lane >> 4;
  f32x4 acc[8];
#pragma unroll
  for(int t=0;t<8;t++) acc[t] = (f32x4){0.f,0.f,0.f,0.f};

  int arow = m0 + lr;
  int ar = arow < M ? arow : (M-1);

#pragma unroll
  for(int ks=0;ks<K;ks+=32){
    const int kb = ks + kg*8;
    bf16x8 ahi, alo;
    splitbf8(&A[(size_t)ar*K + kb], ahi, alo);
#pragma unroll
    for(int t=0;t<8;t++){
      const bf16x8 bh = *(const bf16x8*)&Whi[(size_t)(t*16+lr)*K + kb];
      const bf16x8 bl = *(const bf16x8*)&Wlo[(size_t)(t*16+lr)*K + kb];
      acc[t] = mfma16(ahi, bh, acc[t]);
      acc[t] = mfma16(ahi, bl, acc[t]);
      acc[t] = mfma16(alo, bh, acc[t]);
    }
  }

  float p1[4] = {0.f,0.f,0.f,0.f};
  float p2[4] = {0.f,0.f,0.f,0.f};
#pragma unroll
  for(int t=0;t<8;t++){
    int c = t*16 + lr;
    float ut = (NDOT>=1) ? u[c] : 0.f;
    float vt = (NDOT>=2) ? v[c] : 0.f;
#pragma unroll
    for(int r=0;r<4;r++){
      int m = m0 + kg*4 + r;
      float val = acc[t][r];
      if(ACT==1) val = leakyf(val + bias[c]);
      if(m < M) C[(size_t)m*HH + c] = val;
      if(NDOT>=1) p1[r] += val*ut;
      if(NDOT>=2) p2[r] += val*vt;
    }
  }
  if(NDOT>=1){
#pragma unroll
    for(int r=0;r<4;r++){
      float s1 = wsum16(p1[r]);
      int m = m0 + kg*4 + r;
      if(lr==0 && m < M) douta[m] = s1;
      if(NDOT>=2){
        float s2 = wsum16(p2[r]);
        if(lr==0 && m < M) doutb[m] = s2;
      }
    }
  }
}

// ---------------- fused MFMA GRUCell v3: LDS-staged weights ----------------
// R6 diagnosis: latency-bound (MfmaUtil 5.9%, all pipes idle) — 48 L2 weight loads
// per t-iter per wave, 4x duplicated across waves, no TLP to hide them.
// Fix: per t-group, cooperatively stage the 12 weight regions [16][128] bf16 (48KB)
// into LDS once per block; MFMA reads via swizzled ds_read_b128 (cb ^= row&7 -> 
// balanced 8 dwords/bank = conflict-free for b128).
__global__ __launch_bounds__(256) void k_gru_mfma(const float* __restrict__ MSG,
                                                  const float* __restrict__ X,
                                                  const short* __restrict__ WIhi,
                                                  const short* __restrict__ WIlo,
                                                  const short* __restrict__ WHhi,
                                                  const short* __restrict__ WHlo,
                                                  const float* __restrict__ bih,
                                                  const float* __restrict__ bhh,
                                                  float* __restrict__ XOUT, int M){
  // regions 0..5 = hi {I-r, I-z, I-n, H-r, H-z, H-n}, 6..11 = lo (same order)
  __shared__ short LW[12*16*128];
  const int tid = threadIdx.x;
  const int wave = tid >> 6, lane = tid & 63;
  const int m0 = blockIdx.x*64 + wave*16;
  const int lr = lane & 15, kg = lane >> 4;
  int arow = m0 + lr;
  int ar = arow < M ? arow : (M-1);

  bf16x8 mh[4], ml[4], xh[4], xl[4];
#pragma unroll
  for(int ks=0;ks<4;ks++){
    splitbf8(&MSG[(size_t)ar*HH + ks*32 + kg*8], mh[ks], ml[ks]);
    splitbf8(&X  [(size_t)ar*HH + ks*32 + kg*8], xh[ks], xl[ks]);
  }

  // staging coordinates: thread covers one 16B chunk per region
  const int srow = tid >> 4;                 // 0..15
  const int scb  = tid & 15;                 // 0..15 (16B col-block)
  const int sdst = srow*128 + ((scb ^ (srow & 7))*8);   // swizzled shorts offset in region
  const size_t sgoff = (size_t)srow*HH + scb*8;         // linear global offset in 16-row tile

#pragma unroll 1
  for(int t=0;t<8;t++){
    // ---- stage 12 regions (49KB) ----
#pragma unroll
    for(int r=0;r<12;r++){
      const short* mat = (r<3) ? WIhi : (r<6) ? WHhi : (r<9) ? WIlo : WHlo;
      const int g = (r % 3);
      const short* src = mat + (size_t)(g*128 + t*16)*HH + sgoff;
      *(bf16x8*)&LW[r*2048 + sdst] = *(const bf16x8*)src;
    }
    __syncthreads();

    // ---- compute one gate-triple column group ----
    f32x4 aIr = (f32x4){0.f,0.f,0.f,0.f}, aIz = aIr, aIn = aIr;
    f32x4 aHr = aIr, aHz = aIr, aHn = aIr;
#pragma unroll
    for(int ks=0;ks<4;ks++){
      const int cb = ks*4 + kg;
      const int rb = lr*128 + ((cb ^ (lr & 7))*8);
      bf16x8 bIrh = *(const bf16x8*)&LW[ 0*2048 + rb];
      bf16x8 bIzh = *(const bf16x8*)&LW[ 1*2048 + rb];
      bf16x8 bInh = *(const bf16x8*)&LW[ 2*2048 + rb];
      bf16x8 bHrh = *(const bf16x8*)&LW[ 3*2048 + rb];
      bf16x8 bHzh = *(const bf16x8*)&LW[ 4*2048 + rb];
      bf16x8 bHnh = *(const bf16x8*)&LW[ 5*2048 + rb];
      bf16x8 bIrl = *(const bf16x8*)&LW[ 6*2048 + rb];
      bf16x8 bIzl = *(const bf16x8*)&LW[ 7*2048 + rb];
      bf16x8 bInl = *(const bf16x8*)&LW[ 8*2048 + rb];
      bf16x8 bHrl = *(const bf16x8*)&LW[ 9*2048 + rb];
      bf16x8 bHzl = *(const bf16x8*)&LW[10*2048 + rb];
      bf16x8 bHnl = *(const bf16x8*)&LW[11*2048 + rb];
      aIr = mfma16(mh[ks], bIrh, aIr); aIr = mfma16(mh[ks], bIrl, aIr); aIr = mfma16(ml[ks], bIrh, aIr);
      aIz = mfma16(mh[ks], bIzh, aIz); aIz = mfma16(mh[ks], bIzl, aIz); aIz = mfma16(ml[ks], bIzh, aIz);
      aIn = mfma16(mh[ks], bInh, aIn); aIn = mfma16(mh[ks], bInl, aIn); aIn = mfma16(ml[ks], bInh, aIn);
      aHr = mfma16(xh[ks], bHrh, aHr); aHr = mfma16(xh[ks], bHrl, aHr); aHr = mfma16(xl[ks], bHrh, aHr);
      aHz = mfma16(xh[ks], bHzh, aHz); aHz = mfma16(xh[ks], bHzl, aHz); aHz = mfma16(xl[ks], bHzh, aHz);
      aHn = mfma16(xh[ks], bHnh, aHn); aHn = mfma16(xh[ks], bHnl, aHn); aHn = mfma16(xl[ks], bHnh, aHn);
    }

    const int c = t*16 + lr;
    const float bir = bih[c], biz = bih[c+HH], bin = bih[c+2*HH];
    const float bhr = bhh[c], bhz = bhh[c+HH], bhn = bhh[c+2*HH];
#pragma unroll
    for(int r=0;r<4;r++){
      int mm = m0 + kg*4 + r;
      if(mm < M){
        float ir = aIr[r]+bir, iz = aIz[r]+biz, in_ = aIn[r]+bin;
        float hr = aHr[r]+bhr, hz = aHz[r]+bhz, hn = aHn[r]+bhn;
        float rr = sigmf(ir + hr);
        float z  = sigmf(iz + hz);
        float ng = tanh_fast(in_ + rr*hn);
        float hp = X[(size_t)mm*HH + c];
        XOUT[(size_t)mm*HH + c] = fmaxf((1.f - z)*ng + z*hp, 0.f);
      }
    }
    __syncthreads();   // all reads of LW done before next t's staging
  }
}

// ---------------- GATEConv edge alpha v3 (r6-verified: out of top-5) ----------------
__global__ __launch_bounds__(256) void k_gate_alpha3(const float* __restrict__ XP,
                                                     const float* __restrict__ EA,
                                                     const int* __restrict__ esrc,
                                                     const int* __restrict__ edst,
                                                     const float* __restrict__ W1,
                                                     const float* __restrict__ attl,
                                                     const float* __restrict__ RD,
                                                     const int* __restrict__ eperm,
                                                     const int* __restrict__ eord,
                                                     float* __restrict__ ALPHA){
  __shared__ float W1E[128*16];
  __shared__ float ATTL[128];
  const int tid = threadIdx.x;
#pragma unroll
  for(int q=0;q<8;q++){
    int idx = tid*8 + q;
    int c = idx >> 4, f = idx & 15;
    W1E[idx] = W1[(size_t)c*144 + 128 + f];
  }
  if(tid < 128) ATTL[tid] = attl[tid];
  __syncthreads();

  const int p = blockIdx.x*256 + tid;
  const int eo = eord[p];
  const int s  = esrc[eo];
  const int d  = edst[eo];
  const int pd = eperm[eo];

  float ea[16];
  {
    const float4* g = (const float4*)&EA[(size_t)eo*FE];
    float4 v0=g[0], v1=g[1], v2=g[2], v3=g[3];
    ea[0]=v0.x;ea[1]=v0.y;ea[2]=v0.z;ea[3]=v0.w;
    ea[4]=v1.x;ea[5]=v1.y;ea[6]=v1.z;ea[7]=v1.w;
    ea[8]=v2.x;ea[9]=v2.y;ea[10]=v2.z;ea[11]=v2.w;
    ea[12]=v3.x;ea[13]=v3.y;ea[14]=v3.z;ea[15]=v3.w;
  }

  float acc = 0.f;
#pragma unroll 4
  for(int c0=0;c0<HH;c0+=4){
    float4 xp = *(const float4*)&XP[(size_t)s*HH + c0];
    float xpv[4] = {xp.x, xp.y, xp.z, xp.w};
#pragma unroll
    for(int cc=0;cc<4;cc++){
      const float* wr = &W1E[(c0+cc)*16];
      float eaw = 0.f;
#pragma unroll
      for(int f=0;f<16;f++) eaw += ea[f]*wr[f];
      acc += leakyf(xpv[cc] + eaw) * ATTL[c0+cc];
    }
  }
  ALPHA[pd] = leakyf(acc + RD[d]);
}

// ---------------- segment softmax -> normalized edge weights ----------------
// fast path: degree<=64 -> single gather pass (avg degree 16; fallback kept for safety)
template<int MODE>
__global__ void k_softmaxw(const int* __restrict__ off, const int* __restrict__ items,
                           const float* __restrict__ AIN, const float* __restrict__ A1,
                           const float* __restrict__ A2, float* __restrict__ WOUT, int nseg){
  int w = (blockIdx.x*blockDim.x + threadIdx.x) >> 6;
  int lane = threadIdx.x & 63;
  if(w >= nseg) return;
  int s0 = off[w], s1 = off[w+1];
  int n = s1 - s0;
  float a2 = (MODE==0) ? 0.f : A2[w];

  if(n <= 64){
    float a = -INFINITY;
    int i = s0 + lane;
    if(lane < n){
      if(MODE==0) a = AIN[i];
      else if(MODE==1) a = leakyf(A1[items[i]] + a2);
      else a = leakyf(A1[i] + a2);
    }
    float m = wmax64(a);
    float e = (lane < n) ? __expf(a - m) : 0.f;
    float s = wsum(e);
    if(lane < n) WOUT[i] = e/(s + 1e-16f);
    return;
  }

  float m = -INFINITY;
  for(int i=s0+lane;i<s1;i+=64){
    float a;
    if(MODE==0) a = AIN[i];
    else if(MODE==1) a = leakyf(A1[items[i]] + a2);
    else a = leakyf(A1[i] + a2);
    m = fmaxf(m, a);
  }
  m = wmax64(m);

  float s = 0.f;
  for(int i=s0+lane;i<s1;i+=64){
    float a;
    if(MODE==0) a = AIN[i];
    else if(MODE==1) a = leakyf(A1[items[i]] + a2);
    else a = leakyf(A1[i] + a2);
    s += __expf(a - m);
  }
  s = wsum(s);
  float inv = 1.f/(s + 1e-16f);

  for(int i=s0+lane;i<s1;i+=64){
    float a;
    if(MODE==0) a = AIN[i];
    else if(MODE==1) a = leakyf(A1[items[i]] + a2);
    else a = leakyf(A1[i] + a2);
    WOUT[i] = __expf(a - m)*inv;
  }
}

// ---------------- weighted row gather: OUT[w] = elu(sum_i W[i]*XSrc[it_i] + bias) ----------------
__global__ void k_gather(const int* __restrict__ off, const int* __restrict__ items,
                         const float* __restrict__ W, const float* __restrict__ XSrc,
                         const float* __restrict__ bias, float* __restrict__ OUT, int nseg){
  int w = (blockIdx.x*blockDim.x + threadIdx.x) >> 6;
  int lane = threadIdx.x & 63;
  if(w >= nseg) return;
  int s0 = off[w], s1 = off[w+1];
  float hx = 0.f, hy = 0.f;

  for(int c0=s0;c0<s1;c0+=64){
    int n = min(64, s1-c0);
    int it = 0; float wg = 0.f;
    if(lane < n){
      int i = c0 + lane;
      it = items ? items[i] : i;
      wg = W[i];
    }
#pragma unroll 16
    for(int j=0;j<n;j++){
      int itj = rdl(it, j);
      float wj = rdlf(wg, j);
      float2 xv = *(const float2*)&XSrc[(size_t)itj*HH + 2*lane];
      hx += wj*xv.x;
      hy += wj*xv.y;
    }
  }
  float2 bv = *(const float2*)&bias[2*lane];
  float2 o;
  o.x = eluf(hx + bv.x);
  o.y = eluf(hy + bv.y);
  *(float2*)&OUT[(size_t)w*HH + 2*lane] = o;
}

// ---------------- small per-row kernels ----------------
__global__ void k_dot2(const float* __restrict__ X, const float* __restrict__ u,
                       float* __restrict__ a, int M){
  int w = (blockIdx.x*blockDim.x + threadIdx.x) >> 6;
  int lane = threadIdx.x & 63;
  if(w >= M) return;
  float2 x = *(const float2*)&X[(size_t)w*HH + 2*lane];
  float2 uu = *(const float2*)&u[2*lane];
  float p = x.x*uu.x + x.y*uu.y;
  p = wsum(p);
  if(lane==0) a[w] = p;
}

__global__ void k_ginit(const int* __restrict__ goff, const float* __restrict__ X,
                        float* __restrict__ OUT){
  int g = (blockIdx.x*blockDim.x + threadIdx.x) >> 6;
  int lane = threadIdx.x & 63;
  if(g >= GG) return;
  int s0 = goff[g], s1 = goff[g+1];
  float hx=0.f, hy=0.f;
  for(int n=s0;n<s1;n++){
    float2 xv = *(const float2*)&X[(size_t)n*HH + 2*lane];
    hx += xv.x; hy += xv.y;
  }
  float2 o;
  o.x = fmaxf(hx, 0.f);
  o.y = fmaxf(hy, 0.f);
  *(float2*)&OUT[(size_t)g*HH + 2*lane] = o;
}

// weff[c] = finW·lin2W[:,c]; weff[128] = lin2b·finW + finb; weff[256+c] = mAttD·mLinW[:,c]
__global__ void k_weff(const float* __restrict__ lin2W, const float* __restrict__ lin2b,
                       const float* __restrict__ finW, const float* __restrict__ finb,
                       const float* __restrict__ mLinW, const float* __restrict__ mAttD,
                       float* __restrict__ weff){
  int c = threadIdx.x;
  float s = 0.f, q = 0.f;
  for(int j=0;j<HH;j++){
    s += finW[j]*lin2W[(size_t)j*HH + c];
    q += mAttD[j]*mLinW[(size_t)j*HH + c];
  }
  weff[c] = s;
  weff[256 + c] = q;
  if(c==0){
    float bb = finb[0];
    for(int j=0;j<HH;j++) bb += lin2b[j]*finW[j];
    weff[HH] = bb;
  }
}

__global__ void k_final(const float* __restrict__ OUT, const float* __restrict__ weff,
                        float* __restrict__ y){
  int g = (blockIdx.x*blockDim.x + threadIdx.x) >> 6;
  int lane = threadIdx.x & 63;
  if(g >= GG) return;
  float2 ov = *(const float2*)&OUT[(size_t)g*HH + 2*lane];
  float2 wv = *(const float2*)&weff[2*lane];
  float p = ov.x*wv.x + ov.y*wv.y;
  p = wsum(p);
  if(lane==0) y[g] = sigmf(p + weff[HH]);
}

// ---------------- host ----------------
extern "C" void kernel_launch(void* const* d_in, const int* in_sizes, int n_in,
                              void* d_out, int out_size, void* d_ws, size_t ws_size,
                              hipStream_t stream){
  const float* in_x   = (const float*)d_in[0];
  const int*   eidx   = (const int*)d_in[1];
  const float* ea     = (const float*)d_in[2];
  const int*   batch  = (const int*)d_in[3];
  const float* lin1W  = (const float*)d_in[4];
  const float* lin1b  = (const float*)d_in[5];
  const float* gattl  = (const float*)d_in[6];
  const float* gattr  = (const float*)d_in[7];
  const float* glin1W = (const float*)d_in[8];
  const float* glin2W = (const float*)d_in[9];
  const float* gbias  = (const float*)d_in[10];
  const float* g0Wih  = (const float*)d_in[11];
  const float* g0Whh  = (const float*)d_in[12];
  const float* g0bih  = (const float*)d_in[13];
  const float* g0bhh  = (const float*)d_in[14];
  const float* aLinW  = (const float*)d_in[15];
  const float* aAttS  = (const float*)d_in[16];
  const float* aAttD  = (const float*)d_in[17];
  const float* aBias  = (const float*)d_in[18];
  const float* aGWih  = (const float*)d_in[19];
  const float* aGWhh  = (const float*)d_in[20];
  const float* aGbih  = (const float*)d_in[21];
  const float* aGbhh  = (const float*)d_in[22];
  const float* mLinW  = (const float*)d_in[23];
  const float* mAttS  = (const float*)d_in[24];
  const float* mAttD  = (const float*)d_in[25];
  const float* mBias  = (const float*)d_in[26];
  const float* mGWih  = (const float*)d_in[27];
  const float* mGWhh  = (const float*)d_in[28];
  const float* mGbih  = (const float*)d_in[29];
  const float* mGbhh  = (const float*)d_in[30];
  const float* lin2W  = (const float*)d_in[31];
  const float* lin2b  = (const float*)d_in[32];
  const float* finW   = (const float*)d_in[33];
  const float* finb   = (const float*)d_in[34];

  const int* esrc0 = eidx;
  const int* edst0 = eidx + EE;

  char* w = (char*)d_ws;
  size_t o = 0;
  auto alloc = [&](size_t bytes)->void*{
    void* p = w + o;
    o = (o + bytes + 255) & ~(size_t)255;
    return p;
  };
  float* X    = (float*)alloc((size_t)NN*HH*4);
  float* XB   = (float*)alloc((size_t)NN*HH*4);
  float* XS   = (float*)alloc((size_t)NN*HH*4);
  float* MSG  = (float*)alloc((size_t)NN*HH*4);
  float* XP   = (float*)alloc((size_t)NN*HH*4);
  float* ALPHA= (float*)alloc((size_t)EE*4);
  float* S1   = (float*)alloc((size_t)NN*4);
  float* S2   = (float*)alloc((size_t)NN*4);
  float* ADSTG= (float*)alloc((size_t)GG*4);
  float* OUTg = (float*)alloc((size_t)GG*HH*4);
  float* OUTb = (float*)alloc((size_t)GG*HH*4);
  float* HG   = (float*)alloc((size_t)GG*HH*4);
  float* WEFF = (float*)alloc(512*4);
  short* cWhi = (short*)alloc((size_t)CV_TOT*2);
  short* cWlo = (short*)alloc((size_t)CV_TOT*2);
  int* zeroreg= (int*)alloc((size_t)(4*NN + 2048)*4);
  int* degd = zeroreg;
  int* degs = zeroreg + NN;
  int* curd = zeroreg + 2*NN;
  int* curs = zeroreg + 3*NN;
  int* gcnt = zeroreg + 4*NN;
  int* eoff = (int*)alloc((size_t)(NN+1)*4);
  int* soff = (int*)alloc((size_t)(NN+1)*4);
  int* goff = (int*)alloc((size_t)(GG+1)*4);
  int* esrcS= (int*)alloc((size_t)EE*4);
  int* eperm= (int*)alloc((size_t)EE*4);
  int* eord = (int*)alloc((size_t)EE*4);

  const short* c_lin1_h = cWhi + CV_LIN1; const short* c_lin1_l = cWlo + CV_LIN1;
  const short* c_g1x_h  = cWhi + CV_G1X;  const short* c_g1x_l  = cWlo + CV_G1X;
  const short* c_g2_h   = cWhi + CV_G2;   const short* c_g2_l   = cWlo + CV_G2;
  const short* c_mol_h  = cWhi + CV_MOL;  const short* c_mol_l  = cWlo + CV_MOL;
  const short* c_g0ih_h = cWhi + CV_G0IH; const short* c_g0ih_l = cWlo + CV_G0IH;
  const short* c_g0hh_h = cWhi + CV_G0HH; const short* c_g0hh_l = cWlo + CV_G0HH;
  const short* c_mih_h  = cWhi + CV_MIH;  const short* c_mih_l  = cWlo + CV_MIH;
  const short* c_mhh_h  = cWhi + CV_MHH;  const short* c_mhh_l  = cWlo + CV_MHH;

  // ---- weight pre-split + fused final-layer vectors ----
  k_convw2<<<(CV_TOT+255)/256, 256, 0, stream>>>(lin1W, glin1W, glin2W, aLinW, aGWih, aGWhh,
                                                 mLinW, mGWih, mGWhh, g0Wih, g0Whh, cWhi, cWlo);
  k_weff<<<1, 128, 0, stream>>>(lin2W, lin2b, finW, finb, mLinW, mAttD, WEFF);

  // ---- CSR build (dst-sorted + src-sorted + graph offsets) ----
  hipMemsetAsync(zeroreg, 0, (size_t)(4*NN + 2048)*4, stream);
  k_count_all<<<EE/256, 256, 0, stream>>>(esrc0, edst0, batch, degd, degs, gcnt);
  k_scan3<<<3, 1024, 0, stream>>>(degd, degs, gcnt, eoff, soff, goff);
  k_scatter2<<<EE/256, 256, 0, stream>>>(esrc0, edst0, eoff, soff, curd, curs, esrcS, eperm, eord);

  const int gN = (NN + 63)/64;   // 782
  const int gG = (GG + 63)/64;   // 32

  // ---- input projection (+ fused S1 = X·gattr) ----
  k_proj_mfma<1,64,1><<<gN, 256, 0, stream>>>(in_x, c_lin1_h, c_lin1_l, lin1b, X, NN,
                                              gattr, nullptr, S1, nullptr);

  // ---- GATEConv ----
  k_proj_mfma<0,128,0><<<gN, 256, 0, stream>>>(X, c_g1x_h, c_g1x_l, nullptr, XP, NN,
                                               nullptr, nullptr, nullptr, nullptr);
  k_proj_mfma<0,128,0><<<gN, 256, 0, stream>>>(X, c_g2_h, c_g2_l, nullptr, XS, NN,
                                               nullptr, nullptr, nullptr, nullptr);
  k_gate_alpha3<<<EE/256, 256, 0, stream>>>(XP, ea, esrc0, edst0, glin1W, gattl, S1,
                                            eperm, eord, ALPHA);
  k_softmaxw<0><<<(NN+3)/4, 256, 0, stream>>>(eoff, nullptr, ALPHA, nullptr, nullptr, ALPHA, NN);
  k_gather<<<(NN+3)/4, 256, 0, stream>>>(eoff, esrcS, ALPHA, XS, gbias, MSG, NN);
  k_gru_mfma<<<gN, 256, 0, stream>>>(MSG, X, c_g0ih_h, c_g0ih_l, c_g0hh_h, c_g0hh_l,
                                     g0bih, g0bhh, XB, NN);
  { float* t = X; X = XB; XB = t; }

  // ---- atom GATConv layers ----
  for(int l=0;l<2;l++){
    const short* c_a_h   = cWhi + CV_ALIN + (size_t)l*HH*HH;
    const short* c_a_l   = cWlo + CV_ALIN + (size_t)l*HH*HH;
    const short* c_aih_h = cWhi + CV_AIH + (size_t)l*3*HH*HH;
    const short* c_aih_l = cWlo + CV_AIH + (size_t)l*3*HH*HH;
    const short* c_ahh_h = cWhi + CV_AHH + (size_t)l*3*HH*HH;
    const short* c_ahh_l = cWlo + CV_AHH + (size_t)l*3*HH*HH;
    const float* asl  = aAttS + (size_t)l*HH;
    const float* adl  = aAttD + (size_t)l*HH;
    const float* bl   = aBias + (size_t)l*HH;
    const float* bi   = aGbih + (size_t)l*3*HH;
    const float* bh   = aGbhh + (size_t)l*3*HH;
    k_proj_mfma<0,128,2><<<gN, 256, 0, stream>>>(X, c_a_h, c_a_l, nullptr, XS, NN,
                                                 asl, adl, S1, S2);
    k_softmaxw<1><<<(NN+3)/4, 256, 0, stream>>>(eoff, esrcS, nullptr, S1, S2, ALPHA, NN);
    k_gather<<<(NN+3)/4, 256, 0, stream>>>(eoff, esrcS, ALPHA, XS, bl, MSG, NN);
    k_gru_mfma<<<gN, 256, 0, stream>>>(MSG, X, c_aih_h, c_aih_l, c_ahh_h, c_ahh_l, bi, bh, XB, NN);
    { float* t = X; X = XB; XB = t; }
  }

  // ---- molecule readout ----
  k_ginit<<<(GG+3)/4, 256, 0, stream>>>(goff, X, OUTg);
  k_proj_mfma<0,128,1><<<gN, 256, 0, stream>>>(X, c_mol_h, c_mol_l, nullptr, XS, NN,
                                               mAttS, nullptr, S1, nullptr);

  float* Ocur = OUTg;
  float* Onxt = OUTb;
  for(int t=0;t<3;t++){
    k_dot2<<<(GG+3)/4, 256, 0, stream>>>(Ocur, WEFF+256, ADSTG, GG);
    k_softmaxw<2><<<(GG+3)/4, 256, 0, stream>>>(goff, nullptr, nullptr, S1, ADSTG, ALPHA, GG);
    k_gather<<<(GG+3)/4, 256, 0, stream>>>(goff, nullptr, ALPHA, XS, mBias, HG, GG);
    k_gru_mfma<<<gG, 256, 0, stream>>>(HG, Ocur, c_mih_h, c_mih_l, c_mhh_h, c_mhh_l,
                                       mGbih, mGbhh, Onxt, GG);
    { float* tt = Ocur; Ocur = Onxt; Onxt = tt; }
  }

  // ---- fused lin2 + final ----
  k_final<<<(GG+3)/4, 256, 0, stream>>>(Ocur, WEFF, (float*)d_out);
}